// Round 10
// baseline (672.622 us; speedup 1.0000x reference)
//
#include <hip/hip_runtime.h>
#include <math.h>

#define NN 50000
#define NE 800000

typedef _Float16 half8v __attribute__((ext_vector_type(8)));
typedef _Float16 half4v __attribute__((ext_vector_type(4)));
typedef _Float16 half2v __attribute__((ext_vector_type(2)));
typedef float floatx4 __attribute__((ext_vector_type(4)));

// ---------- helpers ----------
__device__ __forceinline__ float sc_(float s, float m, float mn){
  return (s == 0.f) ? 0.f : s * expf(m - mn);
}
__device__ __forceinline__ void red16(float& v){
  v += __shfl_xor(v, 1, 64); v += __shfl_xor(v, 2, 64);
  v += __shfl_xor(v, 4, 64); v += __shfl_xor(v, 8, 64);
}
__device__ __forceinline__ void lse16(float& m, float& s){
  #pragma unroll
  for (int off = 1; off < 16; off <<= 1){
    float mo = __shfl_xor(m, off, 64), so = __shfl_xor(s, off, 64);
    float mn = fmaxf(m, mo);
    s = sc_(s, m, mn) + sc_(so, mo, mn); m = mn;
  }
}
__device__ __forceinline__ float dot2acc(half2v a, half2v b, float c){
#if __has_builtin(__builtin_amdgcn_fdot2)
  return __builtin_amdgcn_fdot2(a, b, c, false);
#else
  return c + (float)a[0]*(float)b[0] + (float)a[1]*(float)b[1];
#endif
}

// ---------- degree histogram: 4 edges/thread ----------
__launch_bounds__(256)
__global__ void k_hist(const int* __restrict__ ei, int* __restrict__ cs, int* __restrict__ cd){
  int e0 = (blockIdx.x*256 + threadIdx.x)*4;
  if (e0 >= NE) return;
  int4 s = *(const int4*)(ei + e0);
  int4 d = *(const int4*)(ei + NE + e0);
  atomicAdd(&cs[s.x], 1); atomicAdd(&cs[s.y], 1);
  atomicAdd(&cs[s.z], 1); atomicAdd(&cs[s.w], 1);
  atomicAdd(&cd[d.x], 1); atomicAdd(&cd[d.y], 1);
  atomicAdd(&cd[d.z], 1); atomicAdd(&cd[d.w], 1);
}

// ---------- 3-phase exclusive scan ----------
__launch_bounds__(256)
__global__ void k_scan_a(const int* __restrict__ inA, const int* __restrict__ inB,
                         int* __restrict__ outA, int* __restrict__ outB,
                         int* __restrict__ partA, int* __restrict__ partB, int n){
  const int* in = blockIdx.y ? inB : inA;
  int* out = blockIdx.y ? outB : outA;
  int* part = blockIdx.y ? partB : partA;
  int i = blockIdx.x*256 + threadIdx.x;
  int v = (i < n) ? in[i] : 0;
  int lane = threadIdx.x & 63, wid = threadIdx.x >> 6;
  int x = v;
  #pragma unroll
  for (int off = 1; off < 64; off <<= 1){
    int t = __shfl_up(x, off, 64);
    if (lane >= off) x += t;
  }
  __shared__ int wsum[4];
  if (lane == 63) wsum[wid] = x;
  __syncthreads();
  int base = 0;
  #pragma unroll
  for (int w = 0; w < 4; ++w) if (w < wid) base += wsum[w];
  if (i < n) out[i] = base + x - v;
  if (threadIdx.x == 255) part[blockIdx.x] = base + x;
}

__launch_bounds__(256)
__global__ void k_scan_b(int* __restrict__ partA, int* __restrict__ partB, int np){
  int* part = blockIdx.y ? partB : partA;
  int i = threadIdx.x;
  int v = (i < np) ? part[i] : 0;
  int lane = threadIdx.x & 63, wid = threadIdx.x >> 6;
  int x = v;
  #pragma unroll
  for (int off = 1; off < 64; off <<= 1){
    int t = __shfl_up(x, off, 64);
    if (lane >= off) x += t;
  }
  __shared__ int wsum[4];
  if (lane == 63) wsum[wid] = x;
  __syncthreads();
  int base = 0;
  #pragma unroll
  for (int w = 0; w < 4; ++w) if (w < wid) base += wsum[w];
  if (i < np) part[i] = base + x - v;
}

__launch_bounds__(256)
__global__ void k_scan_c(int* __restrict__ outA, int* __restrict__ outB,
                         int* __restrict__ curA, int* __restrict__ curB,
                         const int* __restrict__ partA, const int* __restrict__ partB, int n){
  int* out = blockIdx.y ? outB : outA;
  int* cur = blockIdx.y ? curB : curA;
  const int* part = blockIdx.y ? partB : partA;
  int i = blockIdx.x*256 + threadIdx.x;
  if (i < n){
    int f = out[i] + part[blockIdx.x];
    out[i] = f;
    cur[i] = f;
  }
  if (blockIdx.x == 0 && threadIdx.x == 0) out[n] = NE;
}

// ---------- CSR scatter: 3 random 4B stores, 4 edges/thread (12 stores + 8 atomics MLP) ----------
__launch_bounds__(256)
__global__ void k_scatter(const int* __restrict__ ei, int* __restrict__ cur_s, int* __restrict__ cur_d,
                          int* __restrict__ dst_csr, int* __restrict__ src_dord,
                          int* __restrict__ rs_dord){
  int e0 = (blockIdx.x*256 + threadIdx.x)*4;
  if (e0 >= NE) return;
  int4 ss = *(const int4*)(ei + e0);
  int4 dd = *(const int4*)(ei + NE + e0);
  int js0 = atomicAdd(&cur_s[ss.x], 1);
  int js1 = atomicAdd(&cur_s[ss.y], 1);
  int js2 = atomicAdd(&cur_s[ss.z], 1);
  int js3 = atomicAdd(&cur_s[ss.w], 1);
  int jd0 = atomicAdd(&cur_d[dd.x], 1);
  int jd1 = atomicAdd(&cur_d[dd.y], 1);
  int jd2 = atomicAdd(&cur_d[dd.z], 1);
  int jd3 = atomicAdd(&cur_d[dd.w], 1);
  dst_csr[js0] = dd.x; dst_csr[js1] = dd.y;
  dst_csr[js2] = dd.z; dst_csr[js3] = dd.w;
  src_dord[jd0] = ss.x; src_dord[jd1] = ss.y;
  src_dord[jd2] = ss.z; src_dord[jd3] = ss.w;
  rs_dord[jd0] = js0; rs_dord[jd1] = js1;
  rs_dord[jd2] = js2; rs_dord[jd3] = js3;
}

// ---------- fused setup: weight transpose/f16 + structural table + uint8 degrees ----------
__launch_bounds__(256)
__global__ void k_setup(const float* __restrict__ W0, const float* __restrict__ W1,
                        const float* __restrict__ Wm1, _Float16* __restrict__ Wt,
                        const float* __restrict__ Ws1, const float* __restrict__ bs1,
                        const float* __restrict__ ws2, const float* __restrict__ bs2,
                        float* __restrict__ tab,
                        const int* __restrict__ row_s, const int* __restrict__ row_d,
                        unsigned char* __restrict__ d8o, unsigned char* __restrict__ d8i){
  int b = blockIdx.x;
  if (b < 256){
    int idx = b*256 + threadIdx.x;
    int mat = idx >> 14, rem = idx & 16383;
    int n = rem >> 7, k = rem & 127;
    const float* src = (mat == 0) ? W0 : (mat == 1) ? W1 : (mat == 2) ? Wm1 : (Wm1 + 128*128);
    Wt[idx] = (_Float16)src[k*128 + n];
  } else if (b < 320){
    int idx = (b - 256)*256 + threadIdx.x;
    float du = (float)(idx >> 7), di = (float)(idx & 127);
    float lo = log1pf(du), li = log1pf(di);
    float acc = 0.f;
    for (int c = 0; c < 128; ++c){
      float z = du*Ws1[c] + di*Ws1[128+c] + lo*Ws1[256+c] + li*Ws1[384+c] + bs1[c];
      acc += fmaxf(z, 0.f)*ws2[c];
    }
    tab[idx] = acc + bs2[0];
  } else {
    int n = (b - 320)*256 + threadIdx.x;
    if (n >= NN) return;
    int a = row_s[n+1] - row_s[n];
    int c = row_d[n+1] - row_d[n];
    d8o[n] = (unsigned char)(a > 127 ? 127 : a);
    d8i[n] = (unsigned char)(c > 127 ? 127 : c);
  }
}

// ---------- triple-output MFMA GEMM (operand-swapped) + attention-logit epilogue ----------
template<int AF16, int SECOND>
__launch_bounds__(256)
__global__ void k_gemm3(const void* __restrict__ Ap,
                        const _Float16* __restrict__ Bt0, const _Float16* __restrict__ Bt1,
                        const _Float16* __restrict__ Bt2,
                        const float* __restrict__ bm1,
                        const float* __restrict__ a_s, const float* __restrict__ a_d,
                        _Float16* __restrict__ Hout, _Float16* __restrict__ U01,
                        _Float16* __restrict__ V01,
                        float* __restrict__ alS, float* __restrict__ alD, int M){
  int wv = threadIdx.x >> 6, lane = threadIdx.x & 63;
  int m = lane & 15, q = lane >> 4;
  int row = blockIdx.x*64 + wv*16 + m;
  int arow = (row < M) ? row : (M-1);
  bool wr = (row < M);
  half8v af[4];
  if (AF16){
    const half8v* Ar = (const half8v*)((const _Float16*)Ap + (size_t)arow*128);
    #pragma unroll
    for (int kt = 0; kt < 4; ++kt) af[kt] = Ar[kt*4 + q];
  } else {
    const float* Ar = (const float*)Ap + (size_t)arow*128;
    #pragma unroll
    for (int kt = 0; kt < 4; ++kt){
      const float4* f = (const float4*)(Ar + kt*32 + q*8);
      float4 a0 = f[0], a1 = f[1];
      half8v h;
      h[0]=(_Float16)a0.x; h[1]=(_Float16)a0.y; h[2]=(_Float16)a0.z; h[3]=(_Float16)a0.w;
      h[4]=(_Float16)a1.x; h[5]=(_Float16)a1.y; h[6]=(_Float16)a1.z; h[7]=(_Float16)a1.w;
      af[kt] = h;
    }
  }
  floatx4 acc0[8], acc1[8], acc2[8];
  #pragma unroll
  for (int ct = 0; ct < 8; ++ct){
    #pragma unroll
    for (int r = 0; r < 4; ++r){ acc0[ct][r]=0.f; acc1[ct][r]=0.f; acc2[ct][r]=0.f; }
  }
  #pragma unroll
  for (int ct = 0; ct < 8; ++ct){
    const half8v* Br0 = (const half8v*)(Bt0 + (size_t)(ct*16 + m)*128);
    const half8v* Br1 = (const half8v*)(Bt1 + (size_t)(ct*16 + m)*128);
    const half8v* Br2 = (const half8v*)(Bt2 + (size_t)(ct*16 + m)*128);
    #pragma unroll
    for (int kt = 0; kt < 4; ++kt){
      acc0[ct] = __builtin_amdgcn_mfma_f32_16x16x32_f16(Br0[kt*4 + q], af[kt], acc0[ct], 0, 0, 0);
      acc1[ct] = __builtin_amdgcn_mfma_f32_16x16x32_f16(Br1[kt*4 + q], af[kt], acc1[ct], 0, 0, 0);
      acc2[ct] = __builtin_amdgcn_mfma_f32_16x16x32_f16(Br2[kt*4 + q], af[kt], acc2[ct], 0, 0, 0);
    }
  }
  #pragma unroll
  for (int ct = 0; ct < 8; ++ct){
    float4 asv = *(const float4*)(a_s + ct*16 + q*4);
    float4 adv = *(const float4*)(a_d + ct*16 + q*4);
    float ps = acc0[ct][0]*asv.x + acc0[ct][1]*asv.y + acc0[ct][2]*asv.z + acc0[ct][3]*asv.w;
    float pd = acc0[ct][0]*adv.x + acc0[ct][1]*adv.y + acc0[ct][2]*adv.z + acc0[ct][3]*adv.w;
    ps += __shfl_xor(ps, 16, 64); ps += __shfl_xor(ps, 32, 64);
    pd += __shfl_xor(pd, 16, 64); pd += __shfl_xor(pd, 32, 64);
    if (q == 0 && wr){ alS[row*8 + ct] = ps; alD[row*8 + ct] = pd; }
  }
  if (wr){
    #pragma unroll
    for (int ct = 0; ct < 8; ++ct){
      int cb = ct*16 + q*4;
      float4 bv = *(const float4*)(bm1 + cb);
      if (SECOND == 0){
        half4v h0;
        h0[0]=(_Float16)acc0[ct][0]; h0[1]=(_Float16)acc0[ct][1];
        h0[2]=(_Float16)acc0[ct][2]; h0[3]=(_Float16)acc0[ct][3];
        *(half4v*)(Hout + (size_t)row*128 + cb) = h0;
      }
      half4v h1, h2;
      h1[0]=(_Float16)(acc1[ct][0]+bv.x); h1[1]=(_Float16)(acc1[ct][1]+bv.y);
      h1[2]=(_Float16)(acc1[ct][2]+bv.z); h1[3]=(_Float16)(acc1[ct][3]+bv.w);
      h2[0]=(_Float16)acc2[ct][0]; h2[1]=(_Float16)acc2[ct][1];
      h2[2]=(_Float16)acc2[ct][2]; h2[3]=(_Float16)acc2[ct][3];
      *(half4v*)(U01 + (size_t)row*256 + SECOND*128 + cb) = h1;
      *(half4v*)(V01 + (size_t)row*256 + SECOND*128 + cb) = h2;
    }
  }
}

// ---------- fused per-dst softmax (+optional aggregation), LDS attn cache ----------
template<bool AGG>
__launch_bounds__(256)
__global__ void k_att(const int* __restrict__ row_d, const int* __restrict__ src_dord,
                      const int* __restrict__ rs_dord,
                      const float* __restrict__ alS, const float* __restrict__ alD,
                      const _Float16* __restrict__ H,
                      float* __restrict__ la_csr, _Float16* __restrict__ h1){
  __shared__ float zbuf[4][64*8];
  int wv = threadIdx.x >> 6;
  int node = blockIdx.x*4 + wv;
  if (node >= NN) return;
  int lane = threadIdx.x & 63;
  int j0 = row_d[node], j1 = row_d[node+1];
  int deg = j1 - j0;
  if (deg == 0){
    if (AGG){
      half2v z; z[0] = (_Float16)0; z[1] = (_Float16)0;
      ((half2v*)(h1 + (size_t)node*128))[lane] = z;
    }
    return;
  }
  int head = lane & 7, slot = lane >> 3;
  float ad = alD[node*8 + head];
  float m = -INFINITY, ssum = 0.f;

  if (deg <= 64){
    for (int e = slot; e < deg; e += 8){
      int s = src_dord[j0 + e];
      float z = alS[s*8 + head] + ad;
      z = (z >= 0.f) ? z : 0.2f*z;
      zbuf[wv][e*8 + head] = z;
      float mn = fmaxf(m, z);
      ssum = sc_(ssum, m, mn) + expf(z - mn);
      m = mn;
    }
    #pragma unroll
    for (int off = 8; off < 64; off <<= 1){
      float mo = __shfl_xor(m, off, 64);
      float so = __shfl_xor(ssum, off, 64);
      float mn = fmaxf(m, mo);
      ssum = sc_(ssum, m, mn) + sc_(so, mo, mn);
      m = mn;
    }
    float inv_s = 1.f / ssum;
    for (int e = slot; e < deg; e += 8){
      float a = expf(zbuf[wv][e*8 + head] - m) * inv_s;
      zbuf[wv][e*8 + head] = a;
      float asum = a;
      asum += __shfl_xor(asum, 1, 64);
      asum += __shfl_xor(asum, 2, 64);
      asum += __shfl_xor(asum, 4, 64);
      if (head == 0) la_csr[rs_dord[j0 + e]] = logf(asum*0.125f + 1e-12f);
    }
    if (AGG){
      __asm__ volatile("s_waitcnt lgkmcnt(0)" ::: "memory");
      int h2 = lane >> 3;
      float ax = 0.f, ay = 0.f;
      const half2v* Hv = (const half2v*)H;
      int e = 0;
      for (; e + 1 < deg; e += 2){       // 2-way unroll: independent load chains
        int s0 = src_dord[j0 + e];
        int s1 = src_dord[j0 + e + 1];
        float a0 = zbuf[wv][e*8 + h2];
        float a1 = zbuf[wv][(e+1)*8 + h2];
        half2v hv0 = Hv[(size_t)s0*64 + lane];
        half2v hv1 = Hv[(size_t)s1*64 + lane];
        ax += a0*(float)hv0[0] + a1*(float)hv1[0];
        ay += a0*(float)hv0[1] + a1*(float)hv1[1];
      }
      if (e < deg){
        int s0 = src_dord[j0 + e];
        float a0 = zbuf[wv][e*8 + h2];
        half2v hv0 = Hv[(size_t)s0*64 + lane];
        ax += a0*(float)hv0[0];
        ay += a0*(float)hv0[1];
      }
      ax = (ax > 0.f) ? ax : expm1f(ax);
      ay = (ay > 0.f) ? ay : expm1f(ay);
      half2v o; o[0] = (_Float16)ax; o[1] = (_Float16)ay;
      ((half2v*)(h1 + (size_t)node*128))[lane] = o;
    }
  } else {
    for (int j = j0 + slot; j < j1; j += 8){
      int s = src_dord[j];
      float z = alS[s*8 + head] + ad;
      z = (z >= 0.f) ? z : 0.2f*z;
      float mn = fmaxf(m, z);
      ssum = sc_(ssum, m, mn) + expf(z - mn);
      m = mn;
    }
    #pragma unroll
    for (int off = 8; off < 64; off <<= 1){
      float mo = __shfl_xor(m, off, 64);
      float so = __shfl_xor(ssum, off, 64);
      float mn = fmaxf(m, mo);
      ssum = sc_(ssum, m, mn) + sc_(so, mo, mn);
      m = mn;
    }
    float inv_s = 1.f / ssum;
    for (int j = j0 + slot; j < j1; j += 8){
      int s = src_dord[j];
      float z = alS[s*8 + head] + ad;
      z = (z >= 0.f) ? z : 0.2f*z;
      float a = expf(z - m) * inv_s;
      float asum = a;
      asum += __shfl_xor(asum, 1, 64);
      asum += __shfl_xor(asum, 2, 64);
      asum += __shfl_xor(asum, 4, 64);
      if (head == 0) la_csr[rs_dord[j]] = logf(asum*0.125f + 1e-12f);
    }
    if (AGG){
      int h2 = lane >> 3;
      float m2 = __shfl(m, h2*8, 64);
      float is2 = __shfl(inv_s, h2*8, 64);
      float ad2 = alD[node*8 + h2];
      float ax = 0.f, ay = 0.f;
      const half2v* Hv = (const half2v*)H;
      for (int j = j0; j < j1; ++j){
        int s = src_dord[j];
        float z = alS[s*8 + h2] + ad2;
        z = (z >= 0.f) ? z : 0.2f*z;
        float a = expf(z - m2) * is2;
        half2v hv = Hv[(size_t)s*64 + lane];
        ax += a*(float)hv[0];
        ay += a*(float)hv[1];
      }
      ax = (ax > 0.f) ? ax : expm1f(ax);
      ay = (ay > 0.f) ? ay : expm1f(ay);
      half2v o; o[0] = (_Float16)ax; o[1] = (_Float16)ay;
      ((half2v*)(h1 + (size_t)node*128))[lane] = o;
    }
  }
}

// ---------- per-edge rewards + SVI iteration-1 fold, wave per src node ----------
// outputs 10*r per edge AND V_1[node] = lse over outgoing edges (SVI iter 1, V=0)
__launch_bounds__(256)
__global__ void k_edge7(const int* __restrict__ row_s, const int* __restrict__ dst_csr,
                        const unsigned char* __restrict__ d8o, const unsigned char* __restrict__ d8i,
                        const float* __restrict__ tab,
                        const _Float16* __restrict__ U01, const _Float16* __restrict__ V01,
                        const float* __restrict__ wm2, const float* __restrict__ bm2,
                        const float* __restrict__ lam1,
                        float* __restrict__ rcsr0, float* __restrict__ rcsr1,
                        float* __restrict__ V0out, float* __restrict__ V1out){
  __shared__ _Float16 wml[128];
  if (threadIdx.x < 128) wml[threadIdx.x] = (_Float16)wm2[threadIdx.x];
  __syncthreads();
  int node = blockIdx.x*4 + (threadIdx.x >> 6);
  if (node >= NN) return;
  int lane = threadIdx.x & 63;
  int t = lane & 15, eg = lane >> 4;
  int j0 = row_s[node], j1 = row_s[node+1];
  if (j0 == j1){
    if (lane == 0){ V0out[node] = 0.f; V1out[node] = 0.f; }
    return;
  }
  const half8v* ur = (const half8v*)(U01 + (size_t)node*256);
  half8v u0 = ur[t], u1 = ur[16 + t];
  const half8v* wl = (const half8v*)wml;
  half8v w = wl[t];
  float lam = lam1[0], bb2 = bm2[0];
  int du = (int)d8o[node] << 7;
  float m0 = -INFINITY, s0 = 0.f, m1 = -INFINITY, s1 = 0.f;   // group-local online lse
  for (int j = j0 + eg; j < j1; j += 4){
    int d = dst_csr[j];
    const half8v* vr = (const half8v*)(V01 + (size_t)d*256);
    half8v a = u0 + vr[t];
    half8v b = u1 + vr[16 + t];
    #pragma unroll
    for (int k = 0; k < 8; ++k){
      a[k] = (a[k] > (_Float16)0) ? a[k] : (_Float16)0;
      b[k] = (b[k] > (_Float16)0) ? b[k] : (_Float16)0;
    }
    float r0 = 0.f, r1 = 0.f;
    #pragma unroll
    for (int c = 0; c < 4; ++c){
      half2v aa = {a[2*c], a[2*c+1]};
      half2v bb = {b[2*c], b[2*c+1]};
      half2v ww = {w[2*c], w[2*c+1]};
      r0 = dot2acc(aa, ww, r0);
      r1 = dot2acc(bb, ww, r1);
    }
    red16(r0); red16(r1);
    float rstr = tab[du | (int)d8i[d]];
    float q0 = 10.f*(rstr + lam*(r0 + bb2));
    float q1 = 10.f*(rstr + lam*(r1 + bb2));
    if (t == 0){
      rcsr0[j] = q0;
      rcsr1[j] = q1;
    }
    // online lse update (all 16 lanes of the group redundantly)
    float mn = fmaxf(m0, q0);
    s0 = sc_(s0, m0, mn) + expf(q0 - mn); m0 = mn;
    mn = fmaxf(m1, q1);
    s1 = sc_(s1, m1, mn) + expf(q1 - mn); m1 = mn;
  }
  // merge the 4 edge-groups
  #pragma unroll
  for (int off = 16; off < 64; off <<= 1){
    float mo = __shfl_xor(m0, off, 64), so = __shfl_xor(s0, off, 64);
    float mn = fmaxf(m0, mo);
    s0 = sc_(s0, m0, mn) + sc_(so, mo, mn); m0 = mn;
    mo = __shfl_xor(m1, off, 64); so = __shfl_xor(s1, off, 64);
    mn = fmaxf(m1, mo);
    s1 = sc_(s1, m1, mn) + sc_(so, mo, mn); m1 = mn;
  }
  if (lane == 0){
    V0out[node] = logf(s0) + m0;
    V1out[node] = logf(s1) + m1;
  }
}

// ---------- soft value iteration V-update (both hops), 16 lanes/node ----------
__launch_bounds__(256)
__global__ void k_svi(const int* __restrict__ row_s, const int* __restrict__ dst_csr,
                      const float* __restrict__ r0, const float* __restrict__ r1,
                      const float* __restrict__ V0in, const float* __restrict__ V1in,
                      float* __restrict__ out0, float* __restrict__ out1){
  int node = blockIdx.x*16 + (threadIdx.x >> 4);
  if (node >= NN) return;
  int t = threadIdx.x & 15;
  int j0 = row_s[node], j1 = row_s[node+1];
  if (j0 == j1){
    if (t == 0){ out0[node] = 0.f; out1[node] = 0.f; }
    return;
  }
  float m0 = -INFINITY, s0 = 0.f, m1 = -INFINITY, s1 = 0.f;
  for (int j = j0 + t; j < j1; j += 16){
    int d = dst_csr[j];
    float q0 = r0[j] + V0in[d];
    float q1 = r1[j] + V1in[d];
    float mn0 = fmaxf(m0, q0);
    s0 = sc_(s0, m0, mn0) + expf(q0 - mn0); m0 = mn0;
    float mn1 = fmaxf(m1, q1);
    s1 = sc_(s1, m1, mn1) + expf(q1 - mn1); m1 = mn1;
  }
  lse16(m0, s0); lse16(m1, s1);
  if (t == 0){
    out0[node] = logf(s0) + m0;
    out1[node] = logf(s1) + m1;
  }
}

// ---------- fused: logz + obs-lse + NLL + KL; register-cached deg<=32 fast path ----------
__launch_bounds__(256)
__global__ void k_final2(const int* __restrict__ row_s, const int* __restrict__ dst_csr,
                         const float* __restrict__ la0, const float* __restrict__ la1,
                         const float* __restrict__ r0, const float* __restrict__ r1,
                         const float* __restrict__ V0, const float* __restrict__ V1,
                         float* __restrict__ out, float* __restrict__ partial){
  int node = blockIdx.x*16 + (threadIdx.x >> 4);
  int t = threadIdx.x & 15;
  float nll = 0.f;
  if (node < NN){
    int j0 = row_s[node], j1 = row_s[node+1];
    int deg = j1 - j0;
    if (deg == 0){
      if (t == 0) out[1 + node] = 0.f;
    } else if (deg <= 32){
      int ja = j0 + t, jb = j0 + t + 16;
      float q0a=-INFINITY,q1a=-INFINITY,l0a=-INFINITY,l1a=-INFINITY;
      float q0b=-INFINITY,q1b=-INFINITY,l0b=-INFINITY,l1b=-INFINITY;
      if (ja < j1){
        int d = dst_csr[ja];
        q0a = r0[ja] + V0[d]; q1a = r1[ja] + V1[d];
        l0a = la0[ja]; l1a = la1[ja];
      }
      if (jb < j1){
        int d = dst_csr[jb];
        q0b = r0[jb] + V0[d]; q1b = r1[jb] + V1[d];
        l0b = la0[jb]; l1b = la1[jb];
      }
      float mq0 = fmaxf(q0a, q0b), mq1 = fmaxf(q1a, q1b);
      float ml0 = fmaxf(l0a, l0b), ml1 = fmaxf(l1a, l1b);
      float sq0 = 0.f, sq1 = 0.f, sl0 = 0.f, sl1 = 0.f;
      if (q0a != -INFINITY) sq0 += expf(q0a - mq0);
      if (q0b != -INFINITY) sq0 += expf(q0b - mq0);
      if (q1a != -INFINITY) sq1 += expf(q1a - mq1);
      if (q1b != -INFINITY) sq1 += expf(q1b - mq1);
      if (l0a != -INFINITY) sl0 += expf(l0a - ml0);
      if (l0b != -INFINITY) sl0 += expf(l0b - ml0);
      if (l1a != -INFINITY) sl1 += expf(l1a - ml1);
      if (l1b != -INFINITY) sl1 += expf(l1b - ml1);
      lse16(mq0, sq0); lse16(mq1, sq1); lse16(ml0, sl0); lse16(ml1, sl1);
      float L0 = logf(sq0) + mq0, L1 = logf(sq1) + mq1;
      float O0 = logf(sl0) + ml0, O1 = logf(sl1) + ml1;
      float sca = 0.f;
      if (ja < j1){
        float lp0 = l0a - O0, p0 = expf(lp0), ls0 = q0a - L0;
        nll -= p0*ls0; sca += p0*(lp0 - ls0);
        float lp1 = l1a - O1, p1 = expf(lp1), ls1 = q1a - L1;
        nll -= p1*ls1; sca += p1*(lp1 - ls1);
      }
      if (jb < j1){
        float lp0 = l0b - O0, p0 = expf(lp0), ls0 = q0b - L0;
        nll -= p0*ls0; sca += p0*(lp0 - ls0);
        float lp1 = l1b - O1, p1 = expf(lp1), ls1 = q1b - L1;
        nll -= p1*ls1; sca += p1*(lp1 - ls1);
      }
      red16(sca);
      if (t == 0) out[1 + node] = sca;
    } else {
      float mq0=-INFINITY, sq0=0.f, mq1=-INFINITY, sq1=0.f;
      float ma0=-INFINITY, sa0=0.f, ma1=-INFINITY, sa1=0.f;
      for (int j = j0 + t; j < j1; j += 16){
        int d = dst_csr[j];
        float q0 = r0[j] + V0[d];
        float q1 = r1[j] + V1[d];
        float v0 = la0[j], v1 = la1[j];
        float mn;
        mn = fmaxf(mq0, q0); sq0 = sc_(sq0, mq0, mn) + expf(q0 - mn); mq0 = mn;
        mn = fmaxf(mq1, q1); sq1 = sc_(sq1, mq1, mn) + expf(q1 - mn); mq1 = mn;
        mn = fmaxf(ma0, v0); sa0 = sc_(sa0, ma0, mn) + expf(v0 - mn); ma0 = mn;
        mn = fmaxf(ma1, v1); sa1 = sc_(sa1, ma1, mn) + expf(v1 - mn); ma1 = mn;
      }
      lse16(mq0, sq0); lse16(mq1, sq1); lse16(ma0, sa0); lse16(ma1, sa1);
      float L0 = logf(sq0) + mq0, L1 = logf(sq1) + mq1;
      float O0 = logf(sa0) + ma0, O1 = logf(sa1) + ma1;
      float sca = 0.f;
      for (int j = j0 + t; j < j1; j += 16){
        int d = dst_csr[j];
        float lp0 = la0[j] - O0, p0 = expf(lp0);
        float ls0 = (r0[j] + V0[d]) - L0;
        nll -= p0 * ls0;
        sca += p0 * (lp0 - ls0);
        float lp1 = la1[j] - O1, p1 = expf(lp1);
        float ls1 = (r1[j] + V1[d]) - L1;
        nll -= p1 * ls1;
        sca += p1 * (lp1 - ls1);
      }
      red16(sca);
      if (t == 0) out[1 + node] = sca;
    }
  }
  #pragma unroll
  for (int off = 1; off < 64; off <<= 1) nll += __shfl_xor(nll, off, 64);
  __shared__ float wsum[4];
  if ((threadIdx.x & 63) == 0) wsum[threadIdx.x >> 6] = nll;
  __syncthreads();
  if (threadIdx.x == 0) partial[blockIdx.x] = wsum[0]+wsum[1]+wsum[2]+wsum[3];
}

__launch_bounds__(256)
__global__ void k_nllred(const float* __restrict__ partial, int np, float* __restrict__ out){
  float s = 0.f;
  for (int i = threadIdx.x; i < np; i += 256) s += partial[i];
  #pragma unroll
  for (int off = 1; off < 64; off <<= 1) s += __shfl_xor(s, off, 64);
  __shared__ float wsum[4];
  if ((threadIdx.x & 63) == 0) wsum[threadIdx.x >> 6] = s;
  __syncthreads();
  if (threadIdx.x == 0) out[0] = (wsum[0]+wsum[1]+wsum[2]+wsum[3]) * (1.f/NN);
}

// =======================================================================
extern "C" void kernel_launch(void* const* d_in, const int* in_sizes, int n_in,
                              void* d_out, int out_size, void* d_ws, size_t ws_size,
                              hipStream_t stream){
  const float* x    = (const float*)d_in[0];
  const int*   ei   = (const int*)d_in[1];
  const float* W0   = (const float*)d_in[2];
  const float* as0  = (const float*)d_in[3];
  const float* ad0  = (const float*)d_in[4];
  const float* W1   = (const float*)d_in[5];
  const float* as1  = (const float*)d_in[6];
  const float* ad1  = (const float*)d_in[7];
  const float* Ws1  = (const float*)d_in[8];
  const float* bs1  = (const float*)d_in[9];
  const float* ws2  = (const float*)d_in[10];
  const float* bs2  = (const float*)d_in[11];
  const float* Wm1  = (const float*)d_in[12];
  const float* bm1  = (const float*)d_in[13];
  const float* wm2  = (const float*)d_in[14];
  const float* bm2  = (const float*)d_in[15];
  const float* lam1 = (const float*)d_in[16];
  float* out = (float*)d_out;

  char* p = (char*)d_ws;
  auto alloc = [&](size_t bytes)->void*{
    void* r = (void*)p;
    p += (bytes + 255) & ~(size_t)255;
    return r;
  };
  _Float16* Hh   = (_Float16*)alloc((size_t)NN*128*2);
  _Float16* h1f  = (_Float16*)alloc((size_t)NN*128*2);
  _Float16* U01  = (_Float16*)alloc((size_t)NN*256*2);
  _Float16* V01  = (_Float16*)alloc((size_t)NN*256*2);
  _Float16* Wt   = (_Float16*)alloc((size_t)4*128*128*2);
  float* tab     = (float*)alloc((size_t)128*128*4);
  int*   dst_csr = (int*)alloc((size_t)NE*4);
  int*   src_dord= (int*)alloc((size_t)NE*4);
  int*   rs_dord = (int*)alloc((size_t)NE*4);
  int*   row_s   = (int*)alloc((size_t)(NN+1)*4);
  int*   row_d   = (int*)alloc((size_t)(NN+1)*4);
  int*   cur_s   = (int*)alloc((size_t)NN*4);
  int*   cur_d   = (int*)alloc((size_t)NN*4);
  int*   partA   = (int*)alloc(256*4);
  int*   partB   = (int*)alloc(256*4);
  unsigned char* d8o = (unsigned char*)alloc(NN);
  unsigned char* d8i = (unsigned char*)alloc(NN);
  float* alS     = (float*)alloc((size_t)NN*8*4);
  float* alD     = (float*)alloc((size_t)NN*8*4);
  float* acsr0   = (float*)alloc((size_t)NE*4);
  float* acsr1   = (float*)alloc((size_t)NE*4);
  float* rcsr0   = (float*)alloc((size_t)NE*4);
  float* rcsr1   = (float*)alloc((size_t)NE*4);
  float* V0a = (float*)alloc((size_t)NN*4);
  float* V0b = (float*)alloc((size_t)NN*4);
  float* V1a = (float*)alloc((size_t)NN*4);
  float* V1b = (float*)alloc((size_t)NN*4);
  float* nllpart = (float*)alloc((size_t)4*((NN+15)/16 + 1));

  _Float16* W0t = Wt;
  _Float16* W1t = Wt + 128*128;
  _Float16* Wut = Wt + 2*128*128;
  _Float16* Wvt = Wt + 3*128*128;

  const int G_gemm = (NN + 63)/64;        // 782
  const int G_n4   = (NN + 3)/4;          // 12500
  const int G_n16  = (NN + 15)/16;        // 3125
  const int NPART  = (NN + 255)/256;      // 196
  const int G_setup= 320 + (NN + 255)/256;// 516

  // ---- CSR build ----
  hipMemsetAsync(cur_s, 0, (size_t)NN*4, stream);
  hipMemsetAsync(cur_d, 0, (size_t)NN*4, stream);
  k_hist<<<(NE/4 + 255)/256, 256, 0, stream>>>(ei, cur_s, cur_d);
  k_scan_a<<<dim3(NPART,2), 256, 0, stream>>>(cur_s, cur_d, row_s, row_d, partA, partB, NN);
  k_scan_b<<<dim3(1,2), 256, 0, stream>>>(partA, partB, NPART);
  k_scan_c<<<dim3(NPART,2), 256, 0, stream>>>(row_s, row_d, cur_s, cur_d, partA, partB, NN);
  k_setup<<<G_setup, 256, 0, stream>>>(W0, W1, Wm1, Wt, Ws1, bs1, ws2, bs2, tab,
                                       row_s, row_d, d8o, d8i);
  k_scatter<<<(NE/4 + 255)/256, 256, 0, stream>>>(ei, cur_s, cur_d,
                                                  dst_csr, src_dord, rs_dord);

  // ---- layer 1: x @ {W0, Wu, Wv} + al epilogue ----
  k_gemm3<0,0><<<G_gemm, 256, 0, stream>>>(x, W0t, Wut, Wvt, bm1, as0, ad0,
                                           Hh, U01, V01, alS, alD, NN);
  k_att<true><<<G_n4, 256, 0, stream>>>(row_d, src_dord, rs_dord, alS, alD, Hh, acsr0, h1f);

  // ---- layer 2: h1 @ {W1, Wu, Wv} + al epilogue (no H store) ----
  k_gemm3<1,1><<<G_gemm, 256, 0, stream>>>(h1f, W1t, Wut, Wvt, bm1, as1, ad1,
                                           nullptr, U01, V01, alS, alD, NN);
  k_att<false><<<G_n4, 256, 0, stream>>>(row_d, src_dord, rs_dord, alS, alD, nullptr, acsr1, nullptr);

  // ---- per-edge rewards + SVI iteration 1 (V=0) fused ----
  k_edge7<<<G_n4, 256, 0, stream>>>(row_s, dst_csr, d8o, d8i, tab,
                                    U01, V01, wm2, bm2, lam1, rcsr0, rcsr1, V0b, V1b);

  // ---- SVI iterations 2..5 (4 launches) ----
  float* v0i = V0b; float* v0o = V0a;
  float* v1i = V1b; float* v1o = V1a;
  for (int it = 0; it < 4; ++it){
    k_svi<<<G_n16, 256, 0, stream>>>(row_s, dst_csr, rcsr0, rcsr1, v0i, v1i, v0o, v1o);
    float* t;
    t = v0i; v0i = v0o; v0o = t;
    t = v1i; v1i = v1o; v1o = t;
  }

  // ---- fused logz + obs-lse + loss + score ----
  k_final2<<<G_n16, 256, 0, stream>>>(row_s, dst_csr, acsr0, acsr1, rcsr0, rcsr1,
                                      v0i, v1i, out, nllpart);
  k_nllred<<<1, 256, 0, stream>>>(nllpart, G_n16, out);
}

// Round 11
// 639.418 us; speedup vs baseline: 1.0519x; 1.0519x over previous
//
#include <hip/hip_runtime.h>
#include <math.h>

#define NN 50000
#define NE 800000

typedef _Float16 half8v __attribute__((ext_vector_type(8)));
typedef _Float16 half4v __attribute__((ext_vector_type(4)));
typedef _Float16 half2v __attribute__((ext_vector_type(2)));
typedef float floatx4 __attribute__((ext_vector_type(4)));

// ---------- helpers ----------
__device__ __forceinline__ float sc_(float s, float m, float mn){
  return (s == 0.f) ? 0.f : s * expf(m - mn);
}
__device__ __forceinline__ void red16(float& v){
  v += __shfl_xor(v, 1, 64); v += __shfl_xor(v, 2, 64);
  v += __shfl_xor(v, 4, 64); v += __shfl_xor(v, 8, 64);
}
__device__ __forceinline__ void lse16(float& m, float& s){
  #pragma unroll
  for (int off = 1; off < 16; off <<= 1){
    float mo = __shfl_xor(m, off, 64), so = __shfl_xor(s, off, 64);
    float mn = fmaxf(m, mo);
    s = sc_(s, m, mn) + sc_(so, mo, mn); m = mn;
  }
}
__device__ __forceinline__ float dot2acc(half2v a, half2v b, float c){
#if __has_builtin(__builtin_amdgcn_fdot2)
  return __builtin_amdgcn_fdot2(a, b, c, false);
#else
  return c + (float)a[0]*(float)b[0] + (float)a[1]*(float)b[1];
#endif
}

#define G_HIST 782   // (NE/4 + 255)/256

// ---------- fused pre-pass: degree histogram + weight prep + structural table ----------
__launch_bounds__(256)
__global__ void k_pre(const int* __restrict__ ei, int* __restrict__ cs, int* __restrict__ cd,
                      const float* __restrict__ W0, const float* __restrict__ W1,
                      const float* __restrict__ Wm1, _Float16* __restrict__ Wt,
                      const float* __restrict__ Ws1, const float* __restrict__ bs1,
                      const float* __restrict__ ws2, const float* __restrict__ bs2,
                      float* __restrict__ tab){
  int b = blockIdx.x;
  if (b < G_HIST){                       // histogram, 4 edges/thread
    int e0 = (b*256 + threadIdx.x)*4;
    if (e0 >= NE) return;
    int4 s = *(const int4*)(ei + e0);
    int4 d = *(const int4*)(ei + NE + e0);
    atomicAdd(&cs[s.x], 1); atomicAdd(&cs[s.y], 1);
    atomicAdd(&cs[s.z], 1); atomicAdd(&cs[s.w], 1);
    atomicAdd(&cd[d.x], 1); atomicAdd(&cd[d.y], 1);
    atomicAdd(&cd[d.z], 1); atomicAdd(&cd[d.w], 1);
  } else if (b < G_HIST + 256){          // weight transpose + f16
    int idx = (b - G_HIST)*256 + threadIdx.x;
    int mat = idx >> 14, rem = idx & 16383;
    int n = rem >> 7, k = rem & 127;
    const float* src = (mat == 0) ? W0 : (mat == 1) ? W1 : (mat == 2) ? Wm1 : (Wm1 + 128*128);
    Wt[idx] = (_Float16)src[k*128 + n];
  } else {                               // structural table
    int idx = (b - G_HIST - 256)*256 + threadIdx.x;
    float du = (float)(idx >> 7), di = (float)(idx & 127);
    float lo = log1pf(du), li = log1pf(di);
    float acc = 0.f;
    for (int c = 0; c < 128; ++c){
      float z = du*Ws1[c] + di*Ws1[128+c] + lo*Ws1[256+c] + li*Ws1[384+c] + bs1[c];
      acc += fmaxf(z, 0.f)*ws2[c];
    }
    tab[idx] = acc + bs2[0];
  }
}

// ---------- 3-phase exclusive scan (+ fused uint8 degree from the raw counts) ----------
__launch_bounds__(256)
__global__ void k_scan_a(const int* __restrict__ inA, const int* __restrict__ inB,
                         int* __restrict__ outA, int* __restrict__ outB,
                         int* __restrict__ partA, int* __restrict__ partB,
                         unsigned char* __restrict__ d8o, unsigned char* __restrict__ d8i, int n){
  const int* in = blockIdx.y ? inB : inA;
  int* out = blockIdx.y ? outB : outA;
  int* part = blockIdx.y ? partB : partA;
  unsigned char* d8 = blockIdx.y ? d8i : d8o;
  int i = blockIdx.x*256 + threadIdx.x;
  int v = (i < n) ? in[i] : 0;
  if (i < n) d8[i] = (unsigned char)(v > 127 ? 127 : v);
  int lane = threadIdx.x & 63, wid = threadIdx.x >> 6;
  int x = v;
  #pragma unroll
  for (int off = 1; off < 64; off <<= 1){
    int t = __shfl_up(x, off, 64);
    if (lane >= off) x += t;
  }
  __shared__ int wsum[4];
  if (lane == 63) wsum[wid] = x;
  __syncthreads();
  int base = 0;
  #pragma unroll
  for (int w = 0; w < 4; ++w) if (w < wid) base += wsum[w];
  if (i < n) out[i] = base + x - v;
  if (threadIdx.x == 255) part[blockIdx.x] = base + x;
}

__launch_bounds__(256)
__global__ void k_scan_b(int* __restrict__ partA, int* __restrict__ partB, int np){
  int* part = blockIdx.y ? partB : partA;
  int i = threadIdx.x;
  int v = (i < np) ? part[i] : 0;
  int lane = threadIdx.x & 63, wid = threadIdx.x >> 6;
  int x = v;
  #pragma unroll
  for (int off = 1; off < 64; off <<= 1){
    int t = __shfl_up(x, off, 64);
    if (lane >= off) x += t;
  }
  __shared__ int wsum[4];
  if (lane == 63) wsum[wid] = x;
  __syncthreads();
  int base = 0;
  #pragma unroll
  for (int w = 0; w < 4; ++w) if (w < wid) base += wsum[w];
  if (i < np) part[i] = base + x - v;
}

__launch_bounds__(256)
__global__ void k_scan_c(int* __restrict__ outA, int* __restrict__ outB,
                         int* __restrict__ curA, int* __restrict__ curB,
                         const int* __restrict__ partA, const int* __restrict__ partB, int n){
  int* out = blockIdx.y ? outB : outA;
  int* cur = blockIdx.y ? curB : curA;
  const int* part = blockIdx.y ? partB : partA;
  int i = blockIdx.x*256 + threadIdx.x;
  if (i < n){
    int f = out[i] + part[blockIdx.x];
    out[i] = f;
    cur[i] = f;
  }
  if (blockIdx.x == 0 && threadIdx.x == 0) out[n] = NE;
}

// ---------- CSR scatter: 3 random 4B stores, 4 edges/thread ----------
__launch_bounds__(256)
__global__ void k_scatter(const int* __restrict__ ei, int* __restrict__ cur_s, int* __restrict__ cur_d,
                          int* __restrict__ dst_csr, int* __restrict__ src_dord,
                          int* __restrict__ rs_dord){
  int e0 = (blockIdx.x*256 + threadIdx.x)*4;
  if (e0 >= NE) return;
  int4 ss = *(const int4*)(ei + e0);
  int4 dd = *(const int4*)(ei + NE + e0);
  int js0 = atomicAdd(&cur_s[ss.x], 1);
  int js1 = atomicAdd(&cur_s[ss.y], 1);
  int js2 = atomicAdd(&cur_s[ss.z], 1);
  int js3 = atomicAdd(&cur_s[ss.w], 1);
  int jd0 = atomicAdd(&cur_d[dd.x], 1);
  int jd1 = atomicAdd(&cur_d[dd.y], 1);
  int jd2 = atomicAdd(&cur_d[dd.z], 1);
  int jd3 = atomicAdd(&cur_d[dd.w], 1);
  dst_csr[js0] = dd.x; dst_csr[js1] = dd.y;
  dst_csr[js2] = dd.z; dst_csr[js3] = dd.w;
  src_dord[jd0] = ss.x; src_dord[jd1] = ss.y;
  src_dord[jd2] = ss.z; src_dord[jd3] = ss.w;
  rs_dord[jd0] = js0; rs_dord[jd1] = js1;
  rs_dord[jd2] = js2; rs_dord[jd3] = js3;
}

// ---------- triple-output MFMA GEMM (operand-swapped) + attention-logit epilogue ----------
template<int AF16, int SECOND>
__launch_bounds__(256)
__global__ void k_gemm3(const void* __restrict__ Ap,
                        const _Float16* __restrict__ Bt0, const _Float16* __restrict__ Bt1,
                        const _Float16* __restrict__ Bt2,
                        const float* __restrict__ bm1,
                        const float* __restrict__ a_s, const float* __restrict__ a_d,
                        _Float16* __restrict__ Hout, _Float16* __restrict__ U01,
                        _Float16* __restrict__ V01,
                        float* __restrict__ alS, float* __restrict__ alD, int M){
  int wv = threadIdx.x >> 6, lane = threadIdx.x & 63;
  int m = lane & 15, q = lane >> 4;
  int row = blockIdx.x*64 + wv*16 + m;
  int arow = (row < M) ? row : (M-1);
  bool wr = (row < M);
  half8v af[4];
  if (AF16){
    const half8v* Ar = (const half8v*)((const _Float16*)Ap + (size_t)arow*128);
    #pragma unroll
    for (int kt = 0; kt < 4; ++kt) af[kt] = Ar[kt*4 + q];
  } else {
    const float* Ar = (const float*)Ap + (size_t)arow*128;
    #pragma unroll
    for (int kt = 0; kt < 4; ++kt){
      const float4* f = (const float4*)(Ar + kt*32 + q*8);
      float4 a0 = f[0], a1 = f[1];
      half8v h;
      h[0]=(_Float16)a0.x; h[1]=(_Float16)a0.y; h[2]=(_Float16)a0.z; h[3]=(_Float16)a0.w;
      h[4]=(_Float16)a1.x; h[5]=(_Float16)a1.y; h[6]=(_Float16)a1.z; h[7]=(_Float16)a1.w;
      af[kt] = h;
    }
  }
  floatx4 acc0[8], acc1[8], acc2[8];
  #pragma unroll
  for (int ct = 0; ct < 8; ++ct){
    #pragma unroll
    for (int r = 0; r < 4; ++r){ acc0[ct][r]=0.f; acc1[ct][r]=0.f; acc2[ct][r]=0.f; }
  }
  #pragma unroll
  for (int ct = 0; ct < 8; ++ct){
    const half8v* Br0 = (const half8v*)(Bt0 + (size_t)(ct*16 + m)*128);
    const half8v* Br1 = (const half8v*)(Bt1 + (size_t)(ct*16 + m)*128);
    const half8v* Br2 = (const half8v*)(Bt2 + (size_t)(ct*16 + m)*128);
    #pragma unroll
    for (int kt = 0; kt < 4; ++kt){
      acc0[ct] = __builtin_amdgcn_mfma_f32_16x16x32_f16(Br0[kt*4 + q], af[kt], acc0[ct], 0, 0, 0);
      acc1[ct] = __builtin_amdgcn_mfma_f32_16x16x32_f16(Br1[kt*4 + q], af[kt], acc1[ct], 0, 0, 0);
      acc2[ct] = __builtin_amdgcn_mfma_f32_16x16x32_f16(Br2[kt*4 + q], af[kt], acc2[ct], 0, 0, 0);
    }
  }
  #pragma unroll
  for (int ct = 0; ct < 8; ++ct){
    float4 asv = *(const float4*)(a_s + ct*16 + q*4);
    float4 adv = *(const float4*)(a_d + ct*16 + q*4);
    float ps = acc0[ct][0]*asv.x + acc0[ct][1]*asv.y + acc0[ct][2]*asv.z + acc0[ct][3]*asv.w;
    float pd = acc0[ct][0]*adv.x + acc0[ct][1]*adv.y + acc0[ct][2]*adv.z + acc0[ct][3]*adv.w;
    ps += __shfl_xor(ps, 16, 64); ps += __shfl_xor(ps, 32, 64);
    pd += __shfl_xor(pd, 16, 64); pd += __shfl_xor(pd, 32, 64);
    if (q == 0 && wr){ alS[row*8 + ct] = ps; alD[row*8 + ct] = pd; }
  }
  if (wr){
    #pragma unroll
    for (int ct = 0; ct < 8; ++ct){
      int cb = ct*16 + q*4;
      float4 bv = *(const float4*)(bm1 + cb);
      if (SECOND == 0){
        half4v h0;
        h0[0]=(_Float16)acc0[ct][0]; h0[1]=(_Float16)acc0[ct][1];
        h0[2]=(_Float16)acc0[ct][2]; h0[3]=(_Float16)acc0[ct][3];
        *(half4v*)(Hout + (size_t)row*128 + cb) = h0;
      }
      half4v h1, h2;
      h1[0]=(_Float16)(acc1[ct][0]+bv.x); h1[1]=(_Float16)(acc1[ct][1]+bv.y);
      h1[2]=(_Float16)(acc1[ct][2]+bv.z); h1[3]=(_Float16)(acc1[ct][3]+bv.w);
      h2[0]=(_Float16)acc2[ct][0]; h2[1]=(_Float16)acc2[ct][1];
      h2[2]=(_Float16)acc2[ct][2]; h2[3]=(_Float16)acc2[ct][3];
      *(half4v*)(U01 + (size_t)row*256 + SECOND*128 + cb) = h1;
      *(half4v*)(V01 + (size_t)row*256 + SECOND*128 + cb) = h2;
    }
  }
}

// ---------- layer-1 per-dst softmax + aggregation, LDS attn cache ----------
__launch_bounds__(256)
__global__ void k_att1(const int* __restrict__ row_d, const int* __restrict__ src_dord,
                       const int* __restrict__ rs_dord,
                       const float* __restrict__ alS, const float* __restrict__ alD,
                       const _Float16* __restrict__ H,
                       float* __restrict__ la_csr, _Float16* __restrict__ h1){
  __shared__ float zbuf[4][64*8];
  int wv = threadIdx.x >> 6;
  int node = blockIdx.x*4 + wv;
  if (node >= NN) return;
  int lane = threadIdx.x & 63;
  int j0 = row_d[node], j1 = row_d[node+1];
  int deg = j1 - j0;
  if (deg == 0){
    half2v z; z[0] = (_Float16)0; z[1] = (_Float16)0;
    ((half2v*)(h1 + (size_t)node*128))[lane] = z;
    return;
  }
  int head = lane & 7, slot = lane >> 3;
  float ad = alD[node*8 + head];
  float m = -INFINITY, ssum = 0.f;

  if (deg <= 64){
    for (int e = slot; e < deg; e += 8){
      int s = src_dord[j0 + e];
      float z = alS[s*8 + head] + ad;
      z = (z >= 0.f) ? z : 0.2f*z;
      zbuf[wv][e*8 + head] = z;
      float mn = fmaxf(m, z);
      ssum = sc_(ssum, m, mn) + expf(z - mn);
      m = mn;
    }
    #pragma unroll
    for (int off = 8; off < 64; off <<= 1){
      float mo = __shfl_xor(m, off, 64);
      float so = __shfl_xor(ssum, off, 64);
      float mn = fmaxf(m, mo);
      ssum = sc_(ssum, m, mn) + sc_(so, mo, mn);
      m = mn;
    }
    float inv_s = 1.f / ssum;
    for (int e = slot; e < deg; e += 8){
      float a = expf(zbuf[wv][e*8 + head] - m) * inv_s;
      zbuf[wv][e*8 + head] = a;
      float asum = a;
      asum += __shfl_xor(asum, 1, 64);
      asum += __shfl_xor(asum, 2, 64);
      asum += __shfl_xor(asum, 4, 64);
      if (head == 0) la_csr[rs_dord[j0 + e]] = logf(asum*0.125f + 1e-12f);
    }
    __asm__ volatile("s_waitcnt lgkmcnt(0)" ::: "memory");
    int h2 = lane >> 3;
    float ax = 0.f, ay = 0.f;
    const half2v* Hv = (const half2v*)H;
    int e = 0;
    for (; e + 1 < deg; e += 2){
      int s0 = src_dord[j0 + e];
      int s1 = src_dord[j0 + e + 1];
      float a0 = zbuf[wv][e*8 + h2];
      float a1 = zbuf[wv][(e+1)*8 + h2];
      half2v hv0 = Hv[(size_t)s0*64 + lane];
      half2v hv1 = Hv[(size_t)s1*64 + lane];
      ax += a0*(float)hv0[0] + a1*(float)hv1[0];
      ay += a0*(float)hv0[1] + a1*(float)hv1[1];
    }
    if (e < deg){
      int s0 = src_dord[j0 + e];
      float a0 = zbuf[wv][e*8 + h2];
      half2v hv0 = Hv[(size_t)s0*64 + lane];
      ax += a0*(float)hv0[0];
      ay += a0*(float)hv0[1];
    }
    ax = (ax > 0.f) ? ax : expm1f(ax);
    ay = (ay > 0.f) ? ay : expm1f(ay);
    half2v o; o[0] = (_Float16)ax; o[1] = (_Float16)ay;
    ((half2v*)(h1 + (size_t)node*128))[lane] = o;
  } else {
    for (int j = j0 + slot; j < j1; j += 8){
      int s = src_dord[j];
      float z = alS[s*8 + head] + ad;
      z = (z >= 0.f) ? z : 0.2f*z;
      float mn = fmaxf(m, z);
      ssum = sc_(ssum, m, mn) + expf(z - mn);
      m = mn;
    }
    #pragma unroll
    for (int off = 8; off < 64; off <<= 1){
      float mo = __shfl_xor(m, off, 64);
      float so = __shfl_xor(ssum, off, 64);
      float mn = fmaxf(m, mo);
      ssum = sc_(ssum, m, mn) + sc_(so, mo, mn);
      m = mn;
    }
    float inv_s = 1.f / ssum;
    for (int j = j0 + slot; j < j1; j += 8){
      int s = src_dord[j];
      float z = alS[s*8 + head] + ad;
      z = (z >= 0.f) ? z : 0.2f*z;
      float a = expf(z - m) * inv_s;
      float asum = a;
      asum += __shfl_xor(asum, 1, 64);
      asum += __shfl_xor(asum, 2, 64);
      asum += __shfl_xor(asum, 4, 64);
      if (head == 0) la_csr[rs_dord[j]] = logf(asum*0.125f + 1e-12f);
    }
    int h2 = lane >> 3;
    float m2 = __shfl(m, h2*8, 64);
    float is2 = __shfl(inv_s, h2*8, 64);
    float ad2 = alD[node*8 + h2];
    float ax = 0.f, ay = 0.f;
    const half2v* Hv = (const half2v*)H;
    for (int j = j0; j < j1; ++j){
      int s = src_dord[j];
      float z = alS[s*8 + h2] + ad2;
      z = (z >= 0.f) ? z : 0.2f*z;
      float a = expf(z - m2) * is2;
      half2v hv = Hv[(size_t)s*64 + lane];
      ax += a*(float)hv[0];
      ay += a*(float)hv[1];
    }
    ax = (ax > 0.f) ? ax : expm1f(ax);
    ay = (ay > 0.f) ? ay : expm1f(ay);
    half2v o; o[0] = (_Float16)ax; o[1] = (_Float16)ay;
    ((half2v*)(h1 + (size_t)node*128))[lane] = o;
  }
}

#define G_N4 12500   // (NN+3)/4

// ---------- dual-role: layer-2 softmax (blocks [0,G_N4)) + edge rewards/SVI-1 (blocks [G_N4,2*G_N4)) ----------
// The two roles are independent (both depend only on gemm3<1,1> outputs) and have
// complementary profiles (VALU-heavy vs gather-heavy) -> co-residency overlaps them.
__launch_bounds__(256)
__global__ void k_attedge(const int* __restrict__ row_d, const int* __restrict__ src_dord,
                          const int* __restrict__ rs_dord,
                          const float* __restrict__ alS, const float* __restrict__ alD,
                          float* __restrict__ la_csr,
                          const int* __restrict__ row_s, const int* __restrict__ dst_csr,
                          const unsigned char* __restrict__ d8o, const unsigned char* __restrict__ d8i,
                          const float* __restrict__ tab,
                          const _Float16* __restrict__ U01, const _Float16* __restrict__ V01,
                          const float* __restrict__ wm2, const float* __restrict__ bm2,
                          const float* __restrict__ lam1,
                          float* __restrict__ rcsr0, float* __restrict__ rcsr1,
                          float* __restrict__ V0out, float* __restrict__ V1out){
  __shared__ float lds[4*512];     // att role: zbuf; edge role: first 64 floats = wml(f16 x128)
  if (blockIdx.x < G_N4){
    // ---------------- role A: layer-2 per-dst softmax (head-mean only) ----------------
    float (*zbuf)[512] = (float(*)[512])lds;
    int wv = threadIdx.x >> 6;
    int node = blockIdx.x*4 + wv;
    if (node >= NN) return;
    int lane = threadIdx.x & 63;
    int j0 = row_d[node], j1 = row_d[node+1];
    int deg = j1 - j0;
    if (deg == 0) return;
    int head = lane & 7, slot = lane >> 3;
    float ad = alD[node*8 + head];
    float m = -INFINITY, ssum = 0.f;
    if (deg <= 64){
      for (int e = slot; e < deg; e += 8){
        int s = src_dord[j0 + e];
        float z = alS[s*8 + head] + ad;
        z = (z >= 0.f) ? z : 0.2f*z;
        zbuf[wv][e*8 + head] = z;
        float mn = fmaxf(m, z);
        ssum = sc_(ssum, m, mn) + expf(z - mn);
        m = mn;
      }
      #pragma unroll
      for (int off = 8; off < 64; off <<= 1){
        float mo = __shfl_xor(m, off, 64);
        float so = __shfl_xor(ssum, off, 64);
        float mn = fmaxf(m, mo);
        ssum = sc_(ssum, m, mn) + sc_(so, mo, mn);
        m = mn;
      }
      float inv_s = 1.f / ssum;
      for (int e = slot; e < deg; e += 8){
        float a = expf(zbuf[wv][e*8 + head] - m) * inv_s;
        float asum = a;
        asum += __shfl_xor(asum, 1, 64);
        asum += __shfl_xor(asum, 2, 64);
        asum += __shfl_xor(asum, 4, 64);
        if (head == 0) la_csr[rs_dord[j0 + e]] = logf(asum*0.125f + 1e-12f);
      }
    } else {
      for (int j = j0 + slot; j < j1; j += 8){
        int s = src_dord[j];
        float z = alS[s*8 + head] + ad;
        z = (z >= 0.f) ? z : 0.2f*z;
        float mn = fmaxf(m, z);
        ssum = sc_(ssum, m, mn) + expf(z - mn);
        m = mn;
      }
      #pragma unroll
      for (int off = 8; off < 64; off <<= 1){
        float mo = __shfl_xor(m, off, 64);
        float so = __shfl_xor(ssum, off, 64);
        float mn = fmaxf(m, mo);
        ssum = sc_(ssum, m, mn) + sc_(so, mo, mn);
        m = mn;
      }
      float inv_s = 1.f / ssum;
      for (int j = j0 + slot; j < j1; j += 8){
        int s = src_dord[j];
        float z = alS[s*8 + head] + ad;
        z = (z >= 0.f) ? z : 0.2f*z;
        float a = expf(z - m) * inv_s;
        float asum = a;
        asum += __shfl_xor(asum, 1, 64);
        asum += __shfl_xor(asum, 2, 64);
        asum += __shfl_xor(asum, 4, 64);
        if (head == 0) la_csr[rs_dord[j]] = logf(asum*0.125f + 1e-12f);
      }
    }
  } else {
    // ---------------- role B: per-edge rewards + SVI iteration 1, wave per src node ----------------
    _Float16* wml = (_Float16*)lds;
    if (threadIdx.x < 128) wml[threadIdx.x] = (_Float16)wm2[threadIdx.x];
    __syncthreads();
    int node = (blockIdx.x - G_N4)*4 + (threadIdx.x >> 6);
    if (node >= NN) return;
    int lane = threadIdx.x & 63;
    int t = lane & 15, eg = lane >> 4;
    int j0 = row_s[node], j1 = row_s[node+1];
    if (j0 == j1){
      if (lane == 0){ V0out[node] = 0.f; V1out[node] = 0.f; }
      return;
    }
    const half8v* ur = (const half8v*)(U01 + (size_t)node*256);
    half8v u0 = ur[t], u1 = ur[16 + t];
    const half8v* wl = (const half8v*)wml;
    half8v w = wl[t];
    float lam = lam1[0], bb2 = bm2[0];
    int du = (int)d8o[node] << 7;
    float m0 = -INFINITY, s0 = 0.f, m1 = -INFINITY, s1 = 0.f;
    for (int j = j0 + eg; j < j1; j += 4){
      int d = dst_csr[j];
      const half8v* vr = (const half8v*)(V01 + (size_t)d*256);
      half8v a = u0 + vr[t];
      half8v b = u1 + vr[16 + t];
      #pragma unroll
      for (int k = 0; k < 8; ++k){
        a[k] = (a[k] > (_Float16)0) ? a[k] : (_Float16)0;
        b[k] = (b[k] > (_Float16)0) ? b[k] : (_Float16)0;
      }
      float r0 = 0.f, r1 = 0.f;
      #pragma unroll
      for (int c = 0; c < 4; ++c){
        half2v aa = {a[2*c], a[2*c+1]};
        half2v bb = {b[2*c], b[2*c+1]};
        half2v ww = {w[2*c], w[2*c+1]};
        r0 = dot2acc(aa, ww, r0);
        r1 = dot2acc(bb, ww, r1);
      }
      red16(r0); red16(r1);
      float rstr = tab[du | (int)d8i[d]];
      float q0 = 10.f*(rstr + lam*(r0 + bb2));
      float q1 = 10.f*(rstr + lam*(r1 + bb2));
      if (t == 0){
        rcsr0[j] = q0;
        rcsr1[j] = q1;
      }
      float mn = fmaxf(m0, q0);
      s0 = sc_(s0, m0, mn) + expf(q0 - mn); m0 = mn;
      mn = fmaxf(m1, q1);
      s1 = sc_(s1, m1, mn) + expf(q1 - mn); m1 = mn;
    }
    #pragma unroll
    for (int off = 16; off < 64; off <<= 1){
      float mo = __shfl_xor(m0, off, 64), so = __shfl_xor(s0, off, 64);
      float mn = fmaxf(m0, mo);
      s0 = sc_(s0, m0, mn) + sc_(so, mo, mn); m0 = mn;
      mo = __shfl_xor(m1, off, 64); so = __shfl_xor(s1, off, 64);
      mn = fmaxf(m1, mo);
      s1 = sc_(s1, m1, mn) + sc_(so, mo, mn); m1 = mn;
    }
    if (lane == 0){
      V0out[node] = logf(s0) + m0;
      V1out[node] = logf(s1) + m1;
    }
  }
}

// ---------- soft value iteration V-update (both hops), 16 lanes/node ----------
__launch_bounds__(256)
__global__ void k_svi(const int* __restrict__ row_s, const int* __restrict__ dst_csr,
                      const float* __restrict__ r0, const float* __restrict__ r1,
                      const float* __restrict__ V0in, const float* __restrict__ V1in,
                      float* __restrict__ out0, float* __restrict__ out1){
  int node = blockIdx.x*16 + (threadIdx.x >> 4);
  if (node >= NN) return;
  int t = threadIdx.x & 15;
  int j0 = row_s[node], j1 = row_s[node+1];
  if (j0 == j1){
    if (t == 0){ out0[node] = 0.f; out1[node] = 0.f; }
    return;
  }
  float m0 = -INFINITY, s0 = 0.f, m1 = -INFINITY, s1 = 0.f;
  for (int j = j0 + t; j < j1; j += 16){
    int d = dst_csr[j];
    float q0 = r0[j] + V0in[d];
    float q1 = r1[j] + V1in[d];
    float mn0 = fmaxf(m0, q0);
    s0 = sc_(s0, m0, mn0) + expf(q0 - mn0); m0 = mn0;
    float mn1 = fmaxf(m1, q1);
    s1 = sc_(s1, m1, mn1) + expf(q1 - mn1); m1 = mn1;
  }
  lse16(m0, s0); lse16(m1, s1);
  if (t == 0){
    out0[node] = logf(s0) + m0;
    out1[node] = logf(s1) + m1;
  }
}

// ---------- fused: logz + obs-lse + NLL + KL; register-cached deg<=32 fast path ----------
__launch_bounds__(256)
__global__ void k_final2(const int* __restrict__ row_s, const int* __restrict__ dst_csr,
                         const float* __restrict__ la0, const float* __restrict__ la1,
                         const float* __restrict__ r0, const float* __restrict__ r1,
                         const float* __restrict__ V0, const float* __restrict__ V1,
                         float* __restrict__ out, float* __restrict__ partial){
  int node = blockIdx.x*16 + (threadIdx.x >> 4);
  int t = threadIdx.x & 15;
  float nll = 0.f;
  if (node < NN){
    int j0 = row_s[node], j1 = row_s[node+1];
    int deg = j1 - j0;
    if (deg == 0){
      if (t == 0) out[1 + node] = 0.f;
    } else if (deg <= 32){
      int ja = j0 + t, jb = j0 + t + 16;
      float q0a=-INFINITY,q1a=-INFINITY,l0a=-INFINITY,l1a=-INFINITY;
      float q0b=-INFINITY,q1b=-INFINITY,l0b=-INFINITY,l1b=-INFINITY;
      if (ja < j1){
        int d = dst_csr[ja];
        q0a = r0[ja] + V0[d]; q1a = r1[ja] + V1[d];
        l0a = la0[ja]; l1a = la1[ja];
      }
      if (jb < j1){
        int d = dst_csr[jb];
        q0b = r0[jb] + V0[d]; q1b = r1[jb] + V1[d];
        l0b = la0[jb]; l1b = la1[jb];
      }
      float mq0 = fmaxf(q0a, q0b), mq1 = fmaxf(q1a, q1b);
      float ml0 = fmaxf(l0a, l0b), ml1 = fmaxf(l1a, l1b);
      float sq0 = 0.f, sq1 = 0.f, sl0 = 0.f, sl1 = 0.f;
      if (q0a != -INFINITY) sq0 += expf(q0a - mq0);
      if (q0b != -INFINITY) sq0 += expf(q0b - mq0);
      if (q1a != -INFINITY) sq1 += expf(q1a - mq1);
      if (q1b != -INFINITY) sq1 += expf(q1b - mq1);
      if (l0a != -INFINITY) sl0 += expf(l0a - ml0);
      if (l0b != -INFINITY) sl0 += expf(l0b - ml0);
      if (l1a != -INFINITY) sl1 += expf(l1a - ml1);
      if (l1b != -INFINITY) sl1 += expf(l1b - ml1);
      lse16(mq0, sq0); lse16(mq1, sq1); lse16(ml0, sl0); lse16(ml1, sl1);
      float L0 = logf(sq0) + mq0, L1 = logf(sq1) + mq1;
      float O0 = logf(sl0) + ml0, O1 = logf(sl1) + ml1;
      float sca = 0.f;
      if (ja < j1){
        float lp0 = l0a - O0, p0 = expf(lp0), ls0 = q0a - L0;
        nll -= p0*ls0; sca += p0*(lp0 - ls0);
        float lp1 = l1a - O1, p1 = expf(lp1), ls1 = q1a - L1;
        nll -= p1*ls1; sca += p1*(lp1 - ls1);
      }
      if (jb < j1){
        float lp0 = l0b - O0, p0 = expf(lp0), ls0 = q0b - L0;
        nll -= p0*ls0; sca += p0*(lp0 - ls0);
        float lp1 = l1b - O1, p1 = expf(lp1), ls1 = q1b - L1;
        nll -= p1*ls1; sca += p1*(lp1 - ls1);
      }
      red16(sca);
      if (t == 0) out[1 + node] = sca;
    } else {
      float mq0=-INFINITY, sq0=0.f, mq1=-INFINITY, sq1=0.f;
      float ma0=-INFINITY, sa0=0.f, ma1=-INFINITY, sa1=0.f;
      for (int j = j0 + t; j < j1; j += 16){
        int d = dst_csr[j];
        float q0 = r0[j] + V0[d];
        float q1 = r1[j] + V1[d];
        float v0 = la0[j], v1 = la1[j];
        float mn;
        mn = fmaxf(mq0, q0); sq0 = sc_(sq0, mq0, mn) + expf(q0 - mn); mq0 = mn;
        mn = fmaxf(mq1, q1); sq1 = sc_(sq1, mq1, mn) + expf(q1 - mn); mq1 = mn;
        mn = fmaxf(ma0, v0); sa0 = sc_(sa0, ma0, mn) + expf(v0 - mn); ma0 = mn;
        mn = fmaxf(ma1, v1); sa1 = sc_(sa1, ma1, mn) + expf(v1 - mn); ma1 = mn;
      }
      lse16(mq0, sq0); lse16(mq1, sq1); lse16(ma0, sa0); lse16(ma1, sa1);
      float L0 = logf(sq0) + mq0, L1 = logf(sq1) + mq1;
      float O0 = logf(sa0) + ma0, O1 = logf(sa1) + ma1;
      float sca = 0.f;
      for (int j = j0 + t; j < j1; j += 16){
        int d = dst_csr[j];
        float lp0 = la0[j] - O0, p0 = expf(lp0);
        float ls0 = (r0[j] + V0[d]) - L0;
        nll -= p0 * ls0;
        sca += p0 * (lp0 - ls0);
        float lp1 = la1[j] - O1, p1 = expf(lp1);
        float ls1 = (r1[j] + V1[d]) - L1;
        nll -= p1 * ls1;
        sca += p1 * (lp1 - ls1);
      }
      red16(sca);
      if (t == 0) out[1 + node] = sca;
    }
  }
  #pragma unroll
  for (int off = 1; off < 64; off <<= 1) nll += __shfl_xor(nll, off, 64);
  __shared__ float wsum[4];
  if ((threadIdx.x & 63) == 0) wsum[threadIdx.x >> 6] = nll;
  __syncthreads();
  if (threadIdx.x == 0) partial[blockIdx.x] = wsum[0]+wsum[1]+wsum[2]+wsum[3];
}

__launch_bounds__(256)
__global__ void k_nllred(const float* __restrict__ partial, int np, float* __restrict__ out){
  float s = 0.f;
  for (int i = threadIdx.x; i < np; i += 256) s += partial[i];
  #pragma unroll
  for (int off = 1; off < 64; off <<= 1) s += __shfl_xor(s, off, 64);
  __shared__ float wsum[4];
  if ((threadIdx.x & 63) == 0) wsum[threadIdx.x >> 6] = s;
  __syncthreads();
  if (threadIdx.x == 0) out[0] = (wsum[0]+wsum[1]+wsum[2]+wsum[3]) * (1.f/NN);
}

// =======================================================================
extern "C" void kernel_launch(void* const* d_in, const int* in_sizes, int n_in,
                              void* d_out, int out_size, void* d_ws, size_t ws_size,
                              hipStream_t stream){
  const float* x    = (const float*)d_in[0];
  const int*   ei   = (const int*)d_in[1];
  const float* W0   = (const float*)d_in[2];
  const float* as0  = (const float*)d_in[3];
  const float* ad0  = (const float*)d_in[4];
  const float* W1   = (const float*)d_in[5];
  const float* as1  = (const float*)d_in[6];
  const float* ad1  = (const float*)d_in[7];
  const float* Ws1  = (const float*)d_in[8];
  const float* bs1  = (const float*)d_in[9];
  const float* ws2  = (const float*)d_in[10];
  const float* bs2  = (const float*)d_in[11];
  const float* Wm1  = (const float*)d_in[12];
  const float* bm1  = (const float*)d_in[13];
  const float* wm2  = (const float*)d_in[14];
  const float* bm2  = (const float*)d_in[15];
  const float* lam1 = (const float*)d_in[16];
  float* out = (float*)d_out;

  char* p = (char*)d_ws;
  auto alloc = [&](size_t bytes)->void*{
    void* r = (void*)p;
    p += (bytes + 255) & ~(size_t)255;
    return r;
  };
  _Float16* Hh   = (_Float16*)alloc((size_t)NN*128*2);
  _Float16* h1f  = (_Float16*)alloc((size_t)NN*128*2);
  _Float16* U01  = (_Float16*)alloc((size_t)NN*256*2);
  _Float16* V01  = (_Float16*)alloc((size_t)NN*256*2);
  _Float16* Wt   = (_Float16*)alloc((size_t)4*128*128*2);
  float* tab     = (float*)alloc((size_t)128*128*4);
  int*   dst_csr = (int*)alloc((size_t)NE*4);
  int*   src_dord= (int*)alloc((size_t)NE*4);
  int*   rs_dord = (int*)alloc((size_t)NE*4);
  int*   row_s   = (int*)alloc((size_t)(NN+1)*4);
  int*   row_d   = (int*)alloc((size_t)(NN+1)*4);
  int*   cur_s   = (int*)alloc((size_t)NN*4);
  int*   cur_d   = (int*)alloc((size_t)NN*4);
  int*   partA   = (int*)alloc(256*4);
  int*   partB   = (int*)alloc(256*4);
  unsigned char* d8o = (unsigned char*)alloc(NN);
  unsigned char* d8i = (unsigned char*)alloc(NN);
  float* alS     = (float*)alloc((size_t)NN*8*4);
  float* alD     = (float*)alloc((size_t)NN*8*4);
  float* acsr0   = (float*)alloc((size_t)NE*4);
  float* acsr1   = (float*)alloc((size_t)NE*4);
  float* rcsr0   = (float*)alloc((size_t)NE*4);
  float* rcsr1   = (float*)alloc((size_t)NE*4);
  float* V0a = (float*)alloc((size_t)NN*4);
  float* V0b = (float*)alloc((size_t)NN*4);
  float* V1a = (float*)alloc((size_t)NN*4);
  float* V1b = (float*)alloc((size_t)NN*4);
  float* nllpart = (float*)alloc((size_t)4*((NN+15)/16 + 1));

  _Float16* W0t = Wt;
  _Float16* W1t = Wt + 128*128;
  _Float16* Wut = Wt + 2*128*128;
  _Float16* Wvt = Wt + 3*128*128;

  const int G_gemm = (NN + 63)/64;        // 782
  const int G_n16  = (NN + 15)/16;        // 3125
  const int NPART  = (NN + 255)/256;      // 196
  const int G_pre  = G_HIST + 256 + 64;   // 1102

  // ---- CSR build + setup ----
  hipMemsetAsync(cur_s, 0, (size_t)NN*4, stream);
  hipMemsetAsync(cur_d, 0, (size_t)NN*4, stream);
  k_pre<<<G_pre, 256, 0, stream>>>(ei, cur_s, cur_d, W0, W1, Wm1, Wt,
                                   Ws1, bs1, ws2, bs2, tab);
  k_scan_a<<<dim3(NPART,2), 256, 0, stream>>>(cur_s, cur_d, row_s, row_d, partA, partB,
                                              d8o, d8i, NN);
  k_scan_b<<<dim3(1,2), 256, 0, stream>>>(partA, partB, NPART);
  k_scan_c<<<dim3(NPART,2), 256, 0, stream>>>(row_s, row_d, cur_s, cur_d, partA, partB, NN);
  k_scatter<<<(NE/4 + 255)/256, 256, 0, stream>>>(ei, cur_s, cur_d,
                                                  dst_csr, src_dord, rs_dord);

  // ---- layer 1: x @ {W0, Wu, Wv} + al epilogue ----
  k_gemm3<0,0><<<G_gemm, 256, 0, stream>>>(x, W0t, Wut, Wvt, bm1, as0, ad0,
                                           Hh, U01, V01, alS, alD, NN);
  k_att1<<<G_N4, 256, 0, stream>>>(row_d, src_dord, rs_dord, alS, alD, Hh, acsr0, h1f);

  // ---- layer 2: h1 @ {W1, Wu, Wv} + al epilogue (no H store) ----
  k_gemm3<1,1><<<G_gemm, 256, 0, stream>>>(h1f, W1t, Wut, Wvt, bm1, as1, ad1,
                                           nullptr, U01, V01, alS, alD, NN);

  // ---- dual-role: layer-2 softmax + per-edge rewards/SVI-1 (co-scheduled) ----
  k_attedge<<<2*G_N4, 256, 0, stream>>>(row_d, src_dord, rs_dord, alS, alD, acsr1,
                                        row_s, dst_csr, d8o, d8i, tab,
                                        U01, V01, wm2, bm2, lam1,
                                        rcsr0, rcsr1, V0b, V1b);

  // ---- SVI iterations 2..5 (4 launches) ----
  float* v0i = V0b; float* v0o = V0a;
  float* v1i = V1b; float* v1o = V1a;
  for (int it = 0; it < 4; ++it){
    k_svi<<<G_n16, 256, 0, stream>>>(row_s, dst_csr, rcsr0, rcsr1, v0i, v1i, v0o, v1o);
    float* t;
    t = v0i; v0i = v0o; v0o = t;
    t = v1i; v1i = v1o; v1o = t;
  }

  // ---- fused logz + obs-lse + loss + score ----
  k_final2<<<G_n16, 256, 0, stream>>>(row_s, dst_csr, acsr0, acsr1, rcsr0, rcsr1,
                                      v0i, v1i, out, nllpart);
  k_nllred<<<1, 256, 0, stream>>>(nllpart, G_n16, out);
}

// Round 12
// 627.093 us; speedup vs baseline: 1.0726x; 1.0197x over previous
//
#include <hip/hip_runtime.h>
#include <math.h>

#define NN 50000
#define NE 800000

typedef _Float16 half8v __attribute__((ext_vector_type(8)));
typedef _Float16 half4v __attribute__((ext_vector_type(4)));
typedef _Float16 half2v __attribute__((ext_vector_type(2)));
typedef float floatx4 __attribute__((ext_vector_type(4)));

// ---------- helpers ----------
__device__ __forceinline__ float sc_(float s, float m, float mn){
  return (s == 0.f) ? 0.f : s * expf(m - mn);
}
__device__ __forceinline__ void red16(float& v){
  v += __shfl_xor(v, 1, 64); v += __shfl_xor(v, 2, 64);
  v += __shfl_xor(v, 4, 64); v += __shfl_xor(v, 8, 64);
}
__device__ __forceinline__ void lse16(float& m, float& s){
  #pragma unroll
  for (int off = 1; off < 16; off <<= 1){
    float mo = __shfl_xor(m, off, 64), so = __shfl_xor(s, off, 64);
    float mn = fmaxf(m, mo);
    s = sc_(s, m, mn) + sc_(so, mo, mn); m = mn;
  }
}
__device__ __forceinline__ float dot2acc(half2v a, half2v b, float c){
#if __has_builtin(__builtin_amdgcn_fdot2)
  return __builtin_amdgcn_fdot2(a, b, c, false);
#else
  return c + (float)a[0]*(float)b[0] + (float)a[1]*(float)b[1];
#endif
}

#define G_HIST 782   // (NE/4 + 255)/256
#define G_SCAT 782   // (NE/4 + 255)/256
#define G_GEMM 782   // (NN + 63)/64
#define G_N4 12500   // (NN+3)/4

// ---------- fused pre-pass: degree histogram + weight prep + structural table ----------
__launch_bounds__(256)
__global__ void k_pre(const int* __restrict__ ei, int* __restrict__ cs, int* __restrict__ cd,
                      const float* __restrict__ W0, const float* __restrict__ W1,
                      const float* __restrict__ Wm1, _Float16* __restrict__ Wt,
                      const float* __restrict__ Ws1, const float* __restrict__ bs1,
                      const float* __restrict__ ws2, const float* __restrict__ bs2,
                      float* __restrict__ tab){
  int b = blockIdx.x;
  if (b < G_HIST){                       // histogram, 4 edges/thread
    int e0 = (b*256 + threadIdx.x)*4;
    if (e0 >= NE) return;
    int4 s = *(const int4*)(ei + e0);
    int4 d = *(const int4*)(ei + NE + e0);
    atomicAdd(&cs[s.x], 1); atomicAdd(&cs[s.y], 1);
    atomicAdd(&cs[s.z], 1); atomicAdd(&cs[s.w], 1);
    atomicAdd(&cd[d.x], 1); atomicAdd(&cd[d.y], 1);
    atomicAdd(&cd[d.z], 1); atomicAdd(&cd[d.w], 1);
  } else if (b < G_HIST + 256){          // weight transpose + f16
    int idx = (b - G_HIST)*256 + threadIdx.x;
    int mat = idx >> 14, rem = idx & 16383;
    int n = rem >> 7, k = rem & 127;
    const float* src = (mat == 0) ? W0 : (mat == 1) ? W1 : (mat == 2) ? Wm1 : (Wm1 + 128*128);
    Wt[idx] = (_Float16)src[k*128 + n];
  } else {                               // structural table
    int idx = (b - G_HIST - 256)*256 + threadIdx.x;
    float du = (float)(idx >> 7), di = (float)(idx & 127);
    float lo = log1pf(du), li = log1pf(di);
    float acc = 0.f;
    for (int c = 0; c < 128; ++c){
      float z = du*Ws1[c] + di*Ws1[128+c] + lo*Ws1[256+c] + li*Ws1[384+c] + bs1[c];
      acc += fmaxf(z, 0.f)*ws2[c];
    }
    tab[idx] = acc + bs2[0];
  }
}

// ---------- 3-phase exclusive scan (+ fused uint8 degree from the raw counts) ----------
__launch_bounds__(256)
__global__ void k_scan_a(const int* __restrict__ inA, const int* __restrict__ inB,
                         int* __restrict__ outA, int* __restrict__ outB,
                         int* __restrict__ partA, int* __restrict__ partB,
                         unsigned char* __restrict__ d8o, unsigned char* __restrict__ d8i, int n){
  const int* in = blockIdx.y ? inB : inA;
  int* out = blockIdx.y ? outB : outA;
  int* part = blockIdx.y ? partB : partA;
  unsigned char* d8 = blockIdx.y ? d8i : d8o;
  int i = blockIdx.x*256 + threadIdx.x;
  int v = (i < n) ? in[i] : 0;
  if (i < n) d8[i] = (unsigned char)(v > 127 ? 127 : v);
  int lane = threadIdx.x & 63, wid = threadIdx.x >> 6;
  int x = v;
  #pragma unroll
  for (int off = 1; off < 64; off <<= 1){
    int t = __shfl_up(x, off, 64);
    if (lane >= off) x += t;
  }
  __shared__ int wsum[4];
  if (lane == 63) wsum[wid] = x;
  __syncthreads();
  int base = 0;
  #pragma unroll
  for (int w = 0; w < 4; ++w) if (w < wid) base += wsum[w];
  if (i < n) out[i] = base + x - v;
  if (threadIdx.x == 255) part[blockIdx.x] = base + x;
}

__launch_bounds__(256)
__global__ void k_scan_b(int* __restrict__ partA, int* __restrict__ partB, int np){
  int* part = blockIdx.y ? partB : partA;
  int i = threadIdx.x;
  int v = (i < np) ? part[i] : 0;
  int lane = threadIdx.x & 63, wid = threadIdx.x >> 6;
  int x = v;
  #pragma unroll
  for (int off = 1; off < 64; off <<= 1){
    int t = __shfl_up(x, off, 64);
    if (lane >= off) x += t;
  }
  __shared__ int wsum[4];
  if (lane == 63) wsum[wid] = x;
  __syncthreads();
  int base = 0;
  #pragma unroll
  for (int w = 0; w < 4; ++w) if (w < wid) base += wsum[w];
  if (i < np) part[i] = base + x - v;
}

__launch_bounds__(256)
__global__ void k_scan_c(int* __restrict__ outA, int* __restrict__ outB,
                         int* __restrict__ curA, int* __restrict__ curB,
                         const int* __restrict__ partA, const int* __restrict__ partB, int n){
  int* out = blockIdx.y ? outB : outA;
  int* cur = blockIdx.y ? curB : curA;
  const int* part = blockIdx.y ? partB : partA;
  int i = blockIdx.x*256 + threadIdx.x;
  if (i < n){
    int f = out[i] + part[blockIdx.x];
    out[i] = f;
    cur[i] = f;
  }
  if (blockIdx.x == 0 && threadIdx.x == 0) out[n] = NE;
}

// ---------- dual-role: CSR scatter (blocks [0,G_SCAT)) + layer-1 triple GEMM (rest) ----------
// Independent work items; complementary profiles (random-store latency vs MFMA+streaming).
__launch_bounds__(256)
__global__ void k_scatgemm(const int* __restrict__ ei, int* __restrict__ cur_s, int* __restrict__ cur_d,
                           int* __restrict__ dst_csr, int* __restrict__ src_dord,
                           int* __restrict__ rs_dord,
                           const float* __restrict__ Ap,
                           const _Float16* __restrict__ Bt0, const _Float16* __restrict__ Bt1,
                           const _Float16* __restrict__ Bt2,
                           const float* __restrict__ bm1,
                           const float* __restrict__ a_s, const float* __restrict__ a_d,
                           _Float16* __restrict__ Hout, _Float16* __restrict__ U01,
                           _Float16* __restrict__ V01,
                           float* __restrict__ alS, float* __restrict__ alD){
  if (blockIdx.x < G_SCAT){
    // ---- role A: scatter, 4 edges/thread ----
    int e0 = (blockIdx.x*256 + threadIdx.x)*4;
    if (e0 >= NE) return;
    int4 ss = *(const int4*)(ei + e0);
    int4 dd = *(const int4*)(ei + NE + e0);
    int js0 = atomicAdd(&cur_s[ss.x], 1);
    int js1 = atomicAdd(&cur_s[ss.y], 1);
    int js2 = atomicAdd(&cur_s[ss.z], 1);
    int js3 = atomicAdd(&cur_s[ss.w], 1);
    int jd0 = atomicAdd(&cur_d[dd.x], 1);
    int jd1 = atomicAdd(&cur_d[dd.y], 1);
    int jd2 = atomicAdd(&cur_d[dd.z], 1);
    int jd3 = atomicAdd(&cur_d[dd.w], 1);
    dst_csr[js0] = dd.x; dst_csr[js1] = dd.y;
    dst_csr[js2] = dd.z; dst_csr[js3] = dd.w;
    src_dord[jd0] = ss.x; src_dord[jd1] = ss.y;
    src_dord[jd2] = ss.z; src_dord[jd3] = ss.w;
    rs_dord[jd0] = js0; rs_dord[jd1] = js1;
    rs_dord[jd2] = js2; rs_dord[jd3] = js3;
    return;
  }
  // ---- role B: x @ {W0, Wu, Wv} (operand-swapped MFMA) + al epilogue ----
  int blk = blockIdx.x - G_SCAT;
  int wv = threadIdx.x >> 6, lane = threadIdx.x & 63;
  int m = lane & 15, q = lane >> 4;
  int row = blk*64 + wv*16 + m;
  int arow = (row < NN) ? row : (NN-1);
  bool wr = (row < NN);
  half8v af[4];
  {
    const float* Ar = Ap + (size_t)arow*128;
    #pragma unroll
    for (int kt = 0; kt < 4; ++kt){
      const float4* f = (const float4*)(Ar + kt*32 + q*8);
      float4 a0 = f[0], a1 = f[1];
      half8v h;
      h[0]=(_Float16)a0.x; h[1]=(_Float16)a0.y; h[2]=(_Float16)a0.z; h[3]=(_Float16)a0.w;
      h[4]=(_Float16)a1.x; h[5]=(_Float16)a1.y; h[6]=(_Float16)a1.z; h[7]=(_Float16)a1.w;
      af[kt] = h;
    }
  }
  floatx4 acc0[8], acc1[8], acc2[8];
  #pragma unroll
  for (int ct = 0; ct < 8; ++ct){
    #pragma unroll
    for (int r = 0; r < 4; ++r){ acc0[ct][r]=0.f; acc1[ct][r]=0.f; acc2[ct][r]=0.f; }
  }
  #pragma unroll
  for (int ct = 0; ct < 8; ++ct){
    const half8v* Br0 = (const half8v*)(Bt0 + (size_t)(ct*16 + m)*128);
    const half8v* Br1 = (const half8v*)(Bt1 + (size_t)(ct*16 + m)*128);
    const half8v* Br2 = (const half8v*)(Bt2 + (size_t)(ct*16 + m)*128);
    #pragma unroll
    for (int kt = 0; kt < 4; ++kt){
      acc0[ct] = __builtin_amdgcn_mfma_f32_16x16x32_f16(Br0[kt*4 + q], af[kt], acc0[ct], 0, 0, 0);
      acc1[ct] = __builtin_amdgcn_mfma_f32_16x16x32_f16(Br1[kt*4 + q], af[kt], acc1[ct], 0, 0, 0);
      acc2[ct] = __builtin_amdgcn_mfma_f32_16x16x32_f16(Br2[kt*4 + q], af[kt], acc2[ct], 0, 0, 0);
    }
  }
  #pragma unroll
  for (int ct = 0; ct < 8; ++ct){
    float4 asv = *(const float4*)(a_s + ct*16 + q*4);
    float4 adv = *(const float4*)(a_d + ct*16 + q*4);
    float ps = acc0[ct][0]*asv.x + acc0[ct][1]*asv.y + acc0[ct][2]*asv.z + acc0[ct][3]*asv.w;
    float pd = acc0[ct][0]*adv.x + acc0[ct][1]*adv.y + acc0[ct][2]*adv.z + acc0[ct][3]*adv.w;
    ps += __shfl_xor(ps, 16, 64); ps += __shfl_xor(ps, 32, 64);
    pd += __shfl_xor(pd, 16, 64); pd += __shfl_xor(pd, 32, 64);
    if (q == 0 && wr){ alS[row*8 + ct] = ps; alD[row*8 + ct] = pd; }
  }
  if (wr){
    #pragma unroll
    for (int ct = 0; ct < 8; ++ct){
      int cb = ct*16 + q*4;
      float4 bv = *(const float4*)(bm1 + cb);
      half4v h0, h1, h2;
      h0[0]=(_Float16)acc0[ct][0]; h0[1]=(_Float16)acc0[ct][1];
      h0[2]=(_Float16)acc0[ct][2]; h0[3]=(_Float16)acc0[ct][3];
      *(half4v*)(Hout + (size_t)row*128 + cb) = h0;
      h1[0]=(_Float16)(acc1[ct][0]+bv.x); h1[1]=(_Float16)(acc1[ct][1]+bv.y);
      h1[2]=(_Float16)(acc1[ct][2]+bv.z); h1[3]=(_Float16)(acc1[ct][3]+bv.w);
      h2[0]=(_Float16)acc2[ct][0]; h2[1]=(_Float16)acc2[ct][1];
      h2[2]=(_Float16)acc2[ct][2]; h2[3]=(_Float16)acc2[ct][3];
      *(half4v*)(U01 + (size_t)row*256 + cb) = h1;
      *(half4v*)(V01 + (size_t)row*256 + cb) = h2;
    }
  }
}

// ---------- layer-2 triple-output MFMA GEMM (f16 A, SECOND=1) + al epilogue ----------
__launch_bounds__(256)
__global__ void k_gemm3b(const _Float16* __restrict__ Ap,
                         const _Float16* __restrict__ Bt0, const _Float16* __restrict__ Bt1,
                         const _Float16* __restrict__ Bt2,
                         const float* __restrict__ bm1,
                         const float* __restrict__ a_s, const float* __restrict__ a_d,
                         _Float16* __restrict__ U01, _Float16* __restrict__ V01,
                         float* __restrict__ alS, float* __restrict__ alD){
  int wv = threadIdx.x >> 6, lane = threadIdx.x & 63;
  int m = lane & 15, q = lane >> 4;
  int row = blockIdx.x*64 + wv*16 + m;
  int arow = (row < NN) ? row : (NN-1);
  bool wr = (row < NN);
  half8v af[4];
  {
    const half8v* Ar = (const half8v*)(Ap + (size_t)arow*128);
    #pragma unroll
    for (int kt = 0; kt < 4; ++kt) af[kt] = Ar[kt*4 + q];
  }
  floatx4 acc0[8], acc1[8], acc2[8];
  #pragma unroll
  for (int ct = 0; ct < 8; ++ct){
    #pragma unroll
    for (int r = 0; r < 4; ++r){ acc0[ct][r]=0.f; acc1[ct][r]=0.f; acc2[ct][r]=0.f; }
  }
  #pragma unroll
  for (int ct = 0; ct < 8; ++ct){
    const half8v* Br0 = (const half8v*)(Bt0 + (size_t)(ct*16 + m)*128);
    const half8v* Br1 = (const half8v*)(Bt1 + (size_t)(ct*16 + m)*128);
    const half8v* Br2 = (const half8v*)(Bt2 + (size_t)(ct*16 + m)*128);
    #pragma unroll
    for (int kt = 0; kt < 4; ++kt){
      acc0[ct] = __builtin_amdgcn_mfma_f32_16x16x32_f16(Br0[kt*4 + q], af[kt], acc0[ct], 0, 0, 0);
      acc1[ct] = __builtin_amdgcn_mfma_f32_16x16x32_f16(Br1[kt*4 + q], af[kt], acc1[ct], 0, 0, 0);
      acc2[ct] = __builtin_amdgcn_mfma_f32_16x16x32_f16(Br2[kt*4 + q], af[kt], acc2[ct], 0, 0, 0);
    }
  }
  #pragma unroll
  for (int ct = 0; ct < 8; ++ct){
    float4 asv = *(const float4*)(a_s + ct*16 + q*4);
    float4 adv = *(const float4*)(a_d + ct*16 + q*4);
    float ps = acc0[ct][0]*asv.x + acc0[ct][1]*asv.y + acc0[ct][2]*asv.z + acc0[ct][3]*asv.w;
    float pd = acc0[ct][0]*adv.x + acc0[ct][1]*adv.y + acc0[ct][2]*adv.z + acc0[ct][3]*adv.w;
    ps += __shfl_xor(ps, 16, 64); ps += __shfl_xor(ps, 32, 64);
    pd += __shfl_xor(pd, 16, 64); pd += __shfl_xor(pd, 32, 64);
    if (q == 0 && wr){ alS[row*8 + ct] = ps; alD[row*8 + ct] = pd; }
  }
  if (wr){
    #pragma unroll
    for (int ct = 0; ct < 8; ++ct){
      int cb = ct*16 + q*4;
      float4 bv = *(const float4*)(bm1 + cb);
      half4v h1, h2;
      h1[0]=(_Float16)(acc1[ct][0]+bv.x); h1[1]=(_Float16)(acc1[ct][1]+bv.y);
      h1[2]=(_Float16)(acc1[ct][2]+bv.z); h1[3]=(_Float16)(acc1[ct][3]+bv.w);
      h2[0]=(_Float16)acc2[ct][0]; h2[1]=(_Float16)acc2[ct][1];
      h2[2]=(_Float16)acc2[ct][2]; h2[3]=(_Float16)acc2[ct][3];
      *(half4v*)(U01 + (size_t)row*256 + 128 + cb) = h1;
      *(half4v*)(V01 + (size_t)row*256 + 128 + cb) = h2;
    }
  }
}

// ---------- layer-1 per-dst softmax + aggregation, LDS attn cache ----------
__launch_bounds__(256)
__global__ void k_att1(const int* __restrict__ row_d, const int* __restrict__ src_dord,
                       const int* __restrict__ rs_dord,
                       const float* __restrict__ alS, const float* __restrict__ alD,
                       const _Float16* __restrict__ H,
                       float* __restrict__ la_csr, _Float16* __restrict__ h1){
  __shared__ float zbuf[4][64*8];
  int wv = threadIdx.x >> 6;
  int node = blockIdx.x*4 + wv;
  if (node >= NN) return;
  int lane = threadIdx.x & 63;
  int j0 = row_d[node], j1 = row_d[node+1];
  int deg = j1 - j0;
  if (deg == 0){
    half2v z; z[0] = (_Float16)0; z[1] = (_Float16)0;
    ((half2v*)(h1 + (size_t)node*128))[lane] = z;
    return;
  }
  int head = lane & 7, slot = lane >> 3;
  float ad = alD[node*8 + head];
  float m = -INFINITY, ssum = 0.f;

  if (deg <= 64){
    for (int e = slot; e < deg; e += 8){
      int s = src_dord[j0 + e];
      float z = alS[s*8 + head] + ad;
      z = (z >= 0.f) ? z : 0.2f*z;
      zbuf[wv][e*8 + head] = z;
      float mn = fmaxf(m, z);
      ssum = sc_(ssum, m, mn) + expf(z - mn);
      m = mn;
    }
    #pragma unroll
    for (int off = 8; off < 64; off <<= 1){
      float mo = __shfl_xor(m, off, 64);
      float so = __shfl_xor(ssum, off, 64);
      float mn = fmaxf(m, mo);
      ssum = sc_(ssum, m, mn) + sc_(so, mo, mn);
      m = mn;
    }
    float inv_s = 1.f / ssum;
    for (int e = slot; e < deg; e += 8){
      float a = expf(zbuf[wv][e*8 + head] - m) * inv_s;
      zbuf[wv][e*8 + head] = a;
      float asum = a;
      asum += __shfl_xor(asum, 1, 64);
      asum += __shfl_xor(asum, 2, 64);
      asum += __shfl_xor(asum, 4, 64);
      if (head == 0) la_csr[rs_dord[j0 + e]] = logf(asum*0.125f + 1e-12f);
    }
    __asm__ volatile("s_waitcnt lgkmcnt(0)" ::: "memory");
    int h2 = lane >> 3;
    float ax = 0.f, ay = 0.f;
    const half2v* Hv = (const half2v*)H;
    int e = 0;
    for (; e + 3 < deg; e += 4){     // 4-way unroll: independent load chains
      int s0 = src_dord[j0 + e];
      int s1 = src_dord[j0 + e + 1];
      int s2 = src_dord[j0 + e + 2];
      int s3 = src_dord[j0 + e + 3];
      float a0 = zbuf[wv][e*8 + h2];
      float a1 = zbuf[wv][(e+1)*8 + h2];
      float a2 = zbuf[wv][(e+2)*8 + h2];
      float a3 = zbuf[wv][(e+3)*8 + h2];
      half2v v0 = Hv[(size_t)s0*64 + lane];
      half2v v1 = Hv[(size_t)s1*64 + lane];
      half2v v2 = Hv[(size_t)s2*64 + lane];
      half2v v3 = Hv[(size_t)s3*64 + lane];
      ax += a0*(float)v0[0] + a1*(float)v1[0] + a2*(float)v2[0] + a3*(float)v3[0];
      ay += a0*(float)v0[1] + a1*(float)v1[1] + a2*(float)v2[1] + a3*(float)v3[1];
    }
    for (; e < deg; ++e){
      int s0 = src_dord[j0 + e];
      float a0 = zbuf[wv][e*8 + h2];
      half2v v0 = Hv[(size_t)s0*64 + lane];
      ax += a0*(float)v0[0];
      ay += a0*(float)v0[1];
    }
    ax = (ax > 0.f) ? ax : expm1f(ax);
    ay = (ay > 0.f) ? ay : expm1f(ay);
    half2v o; o[0] = (_Float16)ax; o[1] = (_Float16)ay;
    ((half2v*)(h1 + (size_t)node*128))[lane] = o;
  } else {
    for (int j = j0 + slot; j < j1; j += 8){
      int s = src_dord[j];
      float z = alS[s*8 + head] + ad;
      z = (z >= 0.f) ? z : 0.2f*z;
      float mn = fmaxf(m, z);
      ssum = sc_(ssum, m, mn) + expf(z - mn);
      m = mn;
    }
    #pragma unroll
    for (int off = 8; off < 64; off <<= 1){
      float mo = __shfl_xor(m, off, 64);
      float so = __shfl_xor(ssum, off, 64);
      float mn = fmaxf(m, mo);
      ssum = sc_(ssum, m, mn) + sc_(so, mo, mn);
      m = mn;
    }
    float inv_s = 1.f / ssum;
    for (int j = j0 + slot; j < j1; j += 8){
      int s = src_dord[j];
      float z = alS[s*8 + head] + ad;
      z = (z >= 0.f) ? z : 0.2f*z;
      float a = expf(z - m) * inv_s;
      float asum = a;
      asum += __shfl_xor(asum, 1, 64);
      asum += __shfl_xor(asum, 2, 64);
      asum += __shfl_xor(asum, 4, 64);
      if (head == 0) la_csr[rs_dord[j]] = logf(asum*0.125f + 1e-12f);
    }
    int h2 = lane >> 3;
    float m2 = __shfl(m, h2*8, 64);
    float is2 = __shfl(inv_s, h2*8, 64);
    float ad2 = alD[node*8 + h2];
    float ax = 0.f, ay = 0.f;
    const half2v* Hv = (const half2v*)H;
    for (int j = j0; j < j1; ++j){
      int s = src_dord[j];
      float z = alS[s*8 + h2] + ad2;
      z = (z >= 0.f) ? z : 0.2f*z;
      float a = expf(z - m2) * is2;
      half2v hv = Hv[(size_t)s*64 + lane];
      ax += a*(float)hv[0];
      ay += a*(float)hv[1];
    }
    ax = (ax > 0.f) ? ax : expm1f(ax);
    ay = (ay > 0.f) ? ay : expm1f(ay);
    half2v o; o[0] = (_Float16)ax; o[1] = (_Float16)ay;
    ((half2v*)(h1 + (size_t)node*128))[lane] = o;
  }
}

// ---------- dual-role: layer-2 softmax (blocks [0,G_N4)) + edge rewards/SVI-1 (rest) ----------
__launch_bounds__(256)
__global__ void k_attedge(const int* __restrict__ row_d, const int* __restrict__ src_dord,
                          const int* __restrict__ rs_dord,
                          const float* __restrict__ alS, const float* __restrict__ alD,
                          float* __restrict__ la_csr,
                          const int* __restrict__ row_s, const int* __restrict__ dst_csr,
                          const unsigned char* __restrict__ d8o, const unsigned char* __restrict__ d8i,
                          const float* __restrict__ tab,
                          const _Float16* __restrict__ U01, const _Float16* __restrict__ V01,
                          const float* __restrict__ wm2, const float* __restrict__ bm2,
                          const float* __restrict__ lam1,
                          float* __restrict__ rcsr0, float* __restrict__ rcsr1,
                          float* __restrict__ V0out, float* __restrict__ V1out){
  __shared__ float lds[4*512];
  if (blockIdx.x < G_N4){
    // ---- role A: layer-2 per-dst softmax (head-mean only) ----
    float (*zbuf)[512] = (float(*)[512])lds;
    int wv = threadIdx.x >> 6;
    int node = blockIdx.x*4 + wv;
    if (node >= NN) return;
    int lane = threadIdx.x & 63;
    int j0 = row_d[node], j1 = row_d[node+1];
    int deg = j1 - j0;
    if (deg == 0) return;
    int head = lane & 7, slot = lane >> 3;
    float ad = alD[node*8 + head];
    float m = -INFINITY, ssum = 0.f;
    if (deg <= 64){
      for (int e = slot; e < deg; e += 8){
        int s = src_dord[j0 + e];
        float z = alS[s*8 + head] + ad;
        z = (z >= 0.f) ? z : 0.2f*z;
        zbuf[wv][e*8 + head] = z;
        float mn = fmaxf(m, z);
        ssum = sc_(ssum, m, mn) + expf(z - mn);
        m = mn;
      }
      #pragma unroll
      for (int off = 8; off < 64; off <<= 1){
        float mo = __shfl_xor(m, off, 64);
        float so = __shfl_xor(ssum, off, 64);
        float mn = fmaxf(m, mo);
        ssum = sc_(ssum, m, mn) + sc_(so, mo, mn);
        m = mn;
      }
      float inv_s = 1.f / ssum;
      for (int e = slot; e < deg; e += 8){
        float a = expf(zbuf[wv][e*8 + head] - m) * inv_s;
        float asum = a;
        asum += __shfl_xor(asum, 1, 64);
        asum += __shfl_xor(asum, 2, 64);
        asum += __shfl_xor(asum, 4, 64);
        if (head == 0) la_csr[rs_dord[j0 + e]] = logf(asum*0.125f + 1e-12f);
      }
    } else {
      for (int j = j0 + slot; j < j1; j += 8){
        int s = src_dord[j];
        float z = alS[s*8 + head] + ad;
        z = (z >= 0.f) ? z : 0.2f*z;
        float mn = fmaxf(m, z);
        ssum = sc_(ssum, m, mn) + expf(z - mn);
        m = mn;
      }
      #pragma unroll
      for (int off = 8; off < 64; off <<= 1){
        float mo = __shfl_xor(m, off, 64);
        float so = __shfl_xor(ssum, off, 64);
        float mn = fmaxf(m, mo);
        ssum = sc_(ssum, m, mn) + sc_(so, mo, mn);
        m = mn;
      }
      float inv_s = 1.f / ssum;
      for (int j = j0 + slot; j < j1; j += 8){
        int s = src_dord[j];
        float z = alS[s*8 + head] + ad;
        z = (z >= 0.f) ? z : 0.2f*z;
        float a = expf(z - m) * inv_s;
        float asum = a;
        asum += __shfl_xor(asum, 1, 64);
        asum += __shfl_xor(asum, 2, 64);
        asum += __shfl_xor(asum, 4, 64);
        if (head == 0) la_csr[rs_dord[j]] = logf(asum*0.125f + 1e-12f);
      }
    }
  } else {
    // ---- role B: per-edge rewards + SVI iteration 1 (2-way unrolled V chains) ----
    _Float16* wml = (_Float16*)lds;
    if (threadIdx.x < 128) wml[threadIdx.x] = (_Float16)wm2[threadIdx.x];
    __syncthreads();
    int node = (blockIdx.x - G_N4)*4 + (threadIdx.x >> 6);
    if (node >= NN) return;
    int lane = threadIdx.x & 63;
    int t = lane & 15, eg = lane >> 4;
    int j0 = row_s[node], j1 = row_s[node+1];
    if (j0 == j1){
      if (lane == 0){ V0out[node] = 0.f; V1out[node] = 0.f; }
      return;
    }
    const half8v* ur = (const half8v*)(U01 + (size_t)node*256);
    half8v u0 = ur[t], u1 = ur[16 + t];
    const half8v* wl = (const half8v*)wml;
    half8v w = wl[t];
    float lam = lam1[0], bb2 = bm2[0];
    int du = (int)d8o[node] << 7;
    float m0 = -INFINITY, s0 = 0.f, m1 = -INFINITY, s1 = 0.f;
    int j = j0 + eg;
    for (; j + 4 < j1; j += 8){
      int da = dst_csr[j], db = dst_csr[j+4];
      const half8v* vra = (const half8v*)(V01 + (size_t)da*256);
      const half8v* vrb = (const half8v*)(V01 + (size_t)db*256);
      half8v aa0 = u0 + vra[t], ab0 = u1 + vra[16 + t];
      half8v ba0 = u0 + vrb[t], bb0 = u1 + vrb[16 + t];
      #pragma unroll
      for (int k = 0; k < 8; ++k){
        aa0[k] = (aa0[k] > (_Float16)0) ? aa0[k] : (_Float16)0;
        ab0[k] = (ab0[k] > (_Float16)0) ? ab0[k] : (_Float16)0;
        ba0[k] = (ba0[k] > (_Float16)0) ? ba0[k] : (_Float16)0;
        bb0[k] = (bb0[k] > (_Float16)0) ? bb0[k] : (_Float16)0;
      }
      float r0a = 0.f, r1a = 0.f, r0b = 0.f, r1b = 0.f;
      #pragma unroll
      for (int c = 0; c < 4; ++c){
        half2v ww = {w[2*c], w[2*c+1]};
        half2v x;
        x[0]=aa0[2*c]; x[1]=aa0[2*c+1]; r0a = dot2acc(x, ww, r0a);
        x[0]=ab0[2*c]; x[1]=ab0[2*c+1]; r1a = dot2acc(x, ww, r1a);
        x[0]=ba0[2*c]; x[1]=ba0[2*c+1]; r0b = dot2acc(x, ww, r0b);
        x[0]=bb0[2*c]; x[1]=bb0[2*c+1]; r1b = dot2acc(x, ww, r1b);
      }
      red16(r0a); red16(r1a); red16(r0b); red16(r1b);
      float rstra = tab[du | (int)d8i[da]];
      float rstrb = tab[du | (int)d8i[db]];
      float q0a = 10.f*(rstra + lam*(r0a + bb2));
      float q1a = 10.f*(rstra + lam*(r1a + bb2));
      float q0b = 10.f*(rstrb + lam*(r0b + bb2));
      float q1b = 10.f*(rstrb + lam*(r1b + bb2));
      if (t == 0){
        rcsr0[j] = q0a; rcsr1[j] = q1a;
        rcsr0[j+4] = q0b; rcsr1[j+4] = q1b;
      }
      float mn = fmaxf(m0, fmaxf(q0a, q0b));
      s0 = sc_(s0, m0, mn) + expf(q0a - mn) + expf(q0b - mn); m0 = mn;
      mn = fmaxf(m1, fmaxf(q1a, q1b));
      s1 = sc_(s1, m1, mn) + expf(q1a - mn) + expf(q1b - mn); m1 = mn;
    }
    if (j < j1){
      int d = dst_csr[j];
      const half8v* vr = (const half8v*)(V01 + (size_t)d*256);
      half8v a = u0 + vr[t];
      half8v b = u1 + vr[16 + t];
      #pragma unroll
      for (int k = 0; k < 8; ++k){
        a[k] = (a[k] > (_Float16)0) ? a[k] : (_Float16)0;
        b[k] = (b[k] > (_Float16)0) ? b[k] : (_Float16)0;
      }
      float r0 = 0.f, r1 = 0.f;
      #pragma unroll
      for (int c = 0; c < 4; ++c){
        half2v aa = {a[2*c], a[2*c+1]};
        half2v bb = {b[2*c], b[2*c+1]};
        half2v ww = {w[2*c], w[2*c+1]};
        r0 = dot2acc(aa, ww, r0);
        r1 = dot2acc(bb, ww, r1);
      }
      red16(r0); red16(r1);
      float rstr = tab[du | (int)d8i[d]];
      float q0 = 10.f*(rstr + lam*(r0 + bb2));
      float q1 = 10.f*(rstr + lam*(r1 + bb2));
      if (t == 0){
        rcsr0[j] = q0;
        rcsr1[j] = q1;
      }
      float mn = fmaxf(m0, q0);
      s0 = sc_(s0, m0, mn) + expf(q0 - mn); m0 = mn;
      mn = fmaxf(m1, q1);
      s1 = sc_(s1, m1, mn) + expf(q1 - mn); m1 = mn;
    }
    #pragma unroll
    for (int off = 16; off < 64; off <<= 1){
      float mo = __shfl_xor(m0, off, 64), so = __shfl_xor(s0, off, 64);
      float mn = fmaxf(m0, mo);
      s0 = sc_(s0, m0, mn) + sc_(so, mo, mn); m0 = mn;
      mo = __shfl_xor(m1, off, 64); so = __shfl_xor(s1, off, 64);
      mn = fmaxf(m1, mo);
      s1 = sc_(s1, m1, mn) + sc_(so, mo, mn); m1 = mn;
    }
    if (lane == 0){
      V0out[node] = logf(s0) + m0;
      V1out[node] = logf(s1) + m1;
    }
  }
}

// ---------- soft value iteration V-update (both hops), 16 lanes/node ----------
__launch_bounds__(256)
__global__ void k_svi(const int* __restrict__ row_s, const int* __restrict__ dst_csr,
                      const float* __restrict__ r0, const float* __restrict__ r1,
                      const float* __restrict__ V0in, const float* __restrict__ V1in,
                      float* __restrict__ out0, float* __restrict__ out1){
  int node = blockIdx.x*16 + (threadIdx.x >> 4);
  if (node >= NN) return;
  int t = threadIdx.x & 15;
  int j0 = row_s[node], j1 = row_s[node+1];
  if (j0 == j1){
    if (t == 0){ out0[node] = 0.f; out1[node] = 0.f; }
    return;
  }
  float m0 = -INFINITY, s0 = 0.f, m1 = -INFINITY, s1 = 0.f;
  for (int j = j0 + t; j < j1; j += 16){
    int d = dst_csr[j];
    float q0 = r0[j] + V0in[d];
    float q1 = r1[j] + V1in[d];
    float mn0 = fmaxf(m0, q0);
    s0 = sc_(s0, m0, mn0) + expf(q0 - mn0); m0 = mn0;
    float mn1 = fmaxf(m1, q1);
    s1 = sc_(s1, m1, mn1) + expf(q1 - mn1); m1 = mn1;
  }
  lse16(m0, s0); lse16(m1, s1);
  if (t == 0){
    out0[node] = logf(s0) + m0;
    out1[node] = logf(s1) + m1;
  }
}

// ---------- fused: logz + obs-lse + NLL + KL; register-cached deg<=32 fast path ----------
__launch_bounds__(256)
__global__ void k_final2(const int* __restrict__ row_s, const int* __restrict__ dst_csr,
                         const float* __restrict__ la0, const float* __restrict__ la1,
                         const float* __restrict__ r0, const float* __restrict__ r1,
                         const float* __restrict__ V0, const float* __restrict__ V1,
                         float* __restrict__ out, float* __restrict__ partial){
  int node = blockIdx.x*16 + (threadIdx.x >> 4);
  int t = threadIdx.x & 15;
  float nll = 0.f;
  if (node < NN){
    int j0 = row_s[node], j1 = row_s[node+1];
    int deg = j1 - j0;
    if (deg == 0){
      if (t == 0) out[1 + node] = 0.f;
    } else if (deg <= 32){
      int ja = j0 + t, jb = j0 + t + 16;
      float q0a=-INFINITY,q1a=-INFINITY,l0a=-INFINITY,l1a=-INFINITY;
      float q0b=-INFINITY,q1b=-INFINITY,l0b=-INFINITY,l1b=-INFINITY;
      if (ja < j1){
        int d = dst_csr[ja];
        q0a = r0[ja] + V0[d]; q1a = r1[ja] + V1[d];
        l0a = la0[ja]; l1a = la1[ja];
      }
      if (jb < j1){
        int d = dst_csr[jb];
        q0b = r0[jb] + V0[d]; q1b = r1[jb] + V1[d];
        l0b = la0[jb]; l1b = la1[jb];
      }
      float mq0 = fmaxf(q0a, q0b), mq1 = fmaxf(q1a, q1b);
      float ml0 = fmaxf(l0a, l0b), ml1 = fmaxf(l1a, l1b);
      float sq0 = 0.f, sq1 = 0.f, sl0 = 0.f, sl1 = 0.f;
      if (q0a != -INFINITY) sq0 += expf(q0a - mq0);
      if (q0b != -INFINITY) sq0 += expf(q0b - mq0);
      if (q1a != -INFINITY) sq1 += expf(q1a - mq1);
      if (q1b != -INFINITY) sq1 += expf(q1b - mq1);
      if (l0a != -INFINITY) sl0 += expf(l0a - ml0);
      if (l0b != -INFINITY) sl0 += expf(l0b - ml0);
      if (l1a != -INFINITY) sl1 += expf(l1a - ml1);
      if (l1b != -INFINITY) sl1 += expf(l1b - ml1);
      lse16(mq0, sq0); lse16(mq1, sq1); lse16(ml0, sl0); lse16(ml1, sl1);
      float L0 = logf(sq0) + mq0, L1 = logf(sq1) + mq1;
      float O0 = logf(sl0) + ml0, O1 = logf(sl1) + ml1;
      float sca = 0.f;
      if (ja < j1){
        float lp0 = l0a - O0, p0 = expf(lp0), ls0 = q0a - L0;
        nll -= p0*ls0; sca += p0*(lp0 - ls0);
        float lp1 = l1a - O1, p1 = expf(lp1), ls1 = q1a - L1;
        nll -= p1*ls1; sca += p1*(lp1 - ls1);
      }
      if (jb < j1){
        float lp0 = l0b - O0, p0 = expf(lp0), ls0 = q0b - L0;
        nll -= p0*ls0; sca += p0*(lp0 - ls0);
        float lp1 = l1b - O1, p1 = expf(lp1), ls1 = q1b - L1;
        nll -= p1*ls1; sca += p1*(lp1 - ls1);
      }
      red16(sca);
      if (t == 0) out[1 + node] = sca;
    } else {
      float mq0=-INFINITY, sq0=0.f, mq1=-INFINITY, sq1=0.f;
      float ma0=-INFINITY, sa0=0.f, ma1=-INFINITY, sa1=0.f;
      for (int j = j0 + t; j < j1; j += 16){
        int d = dst_csr[j];
        float q0 = r0[j] + V0[d];
        float q1 = r1[j] + V1[d];
        float v0 = la0[j], v1 = la1[j];
        float mn;
        mn = fmaxf(mq0, q0); sq0 = sc_(sq0, mq0, mn) + expf(q0 - mn); mq0 = mn;
        mn = fmaxf(mq1, q1); sq1 = sc_(sq1, mq1, mn) + expf(q1 - mn); mq1 = mn;
        mn = fmaxf(ma0, v0); sa0 = sc_(sa0, ma0, mn) + expf(v0 - mn); ma0 = mn;
        mn = fmaxf(ma1, v1); sa1 = sc_(sa1, ma1, mn) + expf(v1 - mn); ma1 = mn;
      }
      lse16(mq0, sq0); lse16(mq1, sq1); lse16(ma0, sa0); lse16(ma1, sa1);
      float L0 = logf(sq0) + mq0, L1 = logf(sq1) + mq1;
      float O0 = logf(sa0) + ma0, O1 = logf(sa1) + ma1;
      float sca = 0.f;
      for (int j = j0 + t; j < j1; j += 16){
        int d = dst_csr[j];
        float lp0 = la0[j] - O0, p0 = expf(lp0);
        float ls0 = (r0[j] + V0[d]) - L0;
        nll -= p0 * ls0;
        sca += p0 * (lp0 - ls0);
        float lp1 = la1[j] - O1, p1 = expf(lp1);
        float ls1 = (r1[j] + V1[d]) - L1;
        nll -= p1 * ls1;
        sca += p1 * (lp1 - ls1);
      }
      red16(sca);
      if (t == 0) out[1 + node] = sca;
    }
  }
  #pragma unroll
  for (int off = 1; off < 64; off <<= 1) nll += __shfl_xor(nll, off, 64);
  __shared__ float wsum[4];
  if ((threadIdx.x & 63) == 0) wsum[threadIdx.x >> 6] = nll;
  __syncthreads();
  if (threadIdx.x == 0) partial[blockIdx.x] = wsum[0]+wsum[1]+wsum[2]+wsum[3];
}

__launch_bounds__(256)
__global__ void k_nllred(const float* __restrict__ partial, int np, float* __restrict__ out){
  float s = 0.f;
  for (int i = threadIdx.x; i < np; i += 256) s += partial[i];
  #pragma unroll
  for (int off = 1; off < 64; off <<= 1) s += __shfl_xor(s, off, 64);
  __shared__ float wsum[4];
  if ((threadIdx.x & 63) == 0) wsum[threadIdx.x >> 6] = s;
  __syncthreads();
  if (threadIdx.x == 0) out[0] = (wsum[0]+wsum[1]+wsum[2]+wsum[3]) * (1.f/NN);
}

// =======================================================================
extern "C" void kernel_launch(void* const* d_in, const int* in_sizes, int n_in,
                              void* d_out, int out_size, void* d_ws, size_t ws_size,
                              hipStream_t stream){
  const float* x    = (const float*)d_in[0];
  const int*   ei   = (const int*)d_in[1];
  const float* W0   = (const float*)d_in[2];
  const float* as0  = (const float*)d_in[3];
  const float* ad0  = (const float*)d_in[4];
  const float* W1   = (const float*)d_in[5];
  const float* as1  = (const float*)d_in[6];
  const float* ad1  = (const float*)d_in[7];
  const float* Ws1  = (const float*)d_in[8];
  const float* bs1  = (const float*)d_in[9];
  const float* ws2  = (const float*)d_in[10];
  const float* bs2  = (const float*)d_in[11];
  const float* Wm1  = (const float*)d_in[12];
  const float* bm1  = (const float*)d_in[13];
  const float* wm2  = (const float*)d_in[14];
  const float* bm2  = (const float*)d_in[15];
  const float* lam1 = (const float*)d_in[16];
  float* out = (float*)d_out;

  char* p = (char*)d_ws;
  auto alloc = [&](size_t bytes)->void*{
    void* r = (void*)p;
    p += (bytes + 255) & ~(size_t)255;
    return r;
  };
  _Float16* Hh   = (_Float16*)alloc((size_t)NN*128*2);
  _Float16* h1f  = (_Float16*)alloc((size_t)NN*128*2);
  _Float16* U01  = (_Float16*)alloc((size_t)NN*256*2);
  _Float16* V01  = (_Float16*)alloc((size_t)NN*256*2);
  _Float16* Wt   = (_Float16*)alloc((size_t)4*128*128*2);
  float* tab     = (float*)alloc((size_t)128*128*4);
  int*   dst_csr = (int*)alloc((size_t)NE*4);
  int*   src_dord= (int*)alloc((size_t)NE*4);
  int*   rs_dord = (int*)alloc((size_t)NE*4);
  int*   row_s   = (int*)alloc((size_t)(NN+1)*4);
  int*   row_d   = (int*)alloc((size_t)(NN+1)*4);
  int*   cur_s   = (int*)alloc((size_t)NN*4);
  int*   cur_d   = (int*)alloc((size_t)NN*4);
  int*   partA   = (int*)alloc(256*4);
  int*   partB   = (int*)alloc(256*4);
  unsigned char* d8o = (unsigned char*)alloc(NN);
  unsigned char* d8i = (unsigned char*)alloc(NN);
  float* alS     = (float*)alloc((size_t)NN*8*4);
  float* alD     = (float*)alloc((size_t)NN*8*4);
  float* acsr0   = (float*)alloc((size_t)NE*4);
  float* acsr1   = (float*)alloc((size_t)NE*4);
  float* rcsr0   = (float*)alloc((size_t)NE*4);
  float* rcsr1   = (float*)alloc((size_t)NE*4);
  float* V0a = (float*)alloc((size_t)NN*4);
  float* V0b = (float*)alloc((size_t)NN*4);
  float* V1a = (float*)alloc((size_t)NN*4);
  float* V1b = (float*)alloc((size_t)NN*4);
  float* nllpart = (float*)alloc((size_t)4*((NN+15)/16 + 1));

  _Float16* W0t = Wt;
  _Float16* W1t = Wt + 128*128;
  _Float16* Wut = Wt + 2*128*128;
  _Float16* Wvt = Wt + 3*128*128;

  const int G_n16  = (NN + 15)/16;        // 3125
  const int NPART  = (NN + 255)/256;      // 196
  const int G_pre  = G_HIST + 256 + 64;   // 1102

  // ---- CSR build + setup ----
  hipMemsetAsync(cur_s, 0, (size_t)NN*4, stream);
  hipMemsetAsync(cur_d, 0, (size_t)NN*4, stream);
  k_pre<<<G_pre, 256, 0, stream>>>(ei, cur_s, cur_d, W0, W1, Wm1, Wt,
                                   Ws1, bs1, ws2, bs2, tab);
  k_scan_a<<<dim3(NPART,2), 256, 0, stream>>>(cur_s, cur_d, row_s, row_d, partA, partB,
                                              d8o, d8i, NN);
  k_scan_b<<<dim3(1,2), 256, 0, stream>>>(partA, partB, NPART);
  k_scan_c<<<dim3(NPART,2), 256, 0, stream>>>(row_s, row_d, cur_s, cur_d, partA, partB, NN);

  // ---- dual-role: CSR scatter + layer-1 triple GEMM (independent, co-scheduled) ----
  k_scatgemm<<<G_SCAT + G_GEMM, 256, 0, stream>>>(ei, cur_s, cur_d,
                                                  dst_csr, src_dord, rs_dord,
                                                  x, W0t, Wut, Wvt, bm1, as0, ad0,
                                                  Hh, U01, V01, alS, alD);

  // ---- layer-1 softmax + aggregation ----
  k_att1<<<G_N4, 256, 0, stream>>>(row_d, src_dord, rs_dord, alS, alD, Hh, acsr0, h1f);

  // ---- layer 2: h1 @ {W1, Wu, Wv} + al epilogue ----
  k_gemm3b<<<G_GEMM, 256, 0, stream>>>(h1f, W1t, Wut, Wvt, bm1, as1, ad1,
                                       U01, V01, alS, alD);

  // ---- dual-role: layer-2 softmax + per-edge rewards/SVI-1 ----
  k_attedge<<<2*G_N4, 256, 0, stream>>>(row_d, src_dord, rs_dord, alS, alD, acsr1,
                                        row_s, dst_csr, d8o, d8i, tab,
                                        U01, V01, wm2, bm2, lam1,
                                        rcsr0, rcsr1, V0b, V1b);

  // ---- SVI iterations 2..5 (4 launches) ----
  float* v0i = V0b; float* v0o = V0a;
  float* v1i = V1b; float* v1o = V1a;
  for (int it = 0; it < 4; ++it){
    k_svi<<<G_n16, 256, 0, stream>>>(row_s, dst_csr, rcsr0, rcsr1, v0i, v1i, v0o, v1o);
    float* t;
    t = v0i; v0i = v0o; v0o = t;
    t = v1i; v1i = v1o; v1o = t;
  }

  // ---- fused logz + obs-lse + loss + score ----
  k_final2<<<G_n16, 256, 0, stream>>>(row_s, dst_csr, acsr0, acsr1, rcsr0, rcsr1,
                                      v0i, v1i, out, nllpart);
  k_nllred<<<1, 256, 0, stream>>>(nllpart, G_n16, out);
}